// Round 7
// baseline (811.179 us; speedup 1.0000x reference)
//
#include <hip/hip_runtime.h>

#define HD 64        // hidden == out dim
#define CH 2048      // edges per bin1 block
#define BKT_SHIFT 10 // 1024 nodes per bucket
#define SRC_BITS 17  // N=100000 < 2^17 -> {dstlocal:10 | src:17} fits in 27 bits
#define MAXBLK 1024  // >= NBLK = ceil(E/CH) = 782

typedef __attribute__((ext_vector_type(8))) short bf16x8;
typedef __attribute__((ext_vector_type(4))) float f32x4;

__device__ inline unsigned short f2bf(float x) {
  unsigned u = __float_as_uint(x);
  unsigned r = u + 0x7FFF + ((u >> 16) & 1);
  return (unsigned short)(r >> 16);
}
__device__ inline float bf2f(unsigned short h) {
  return __uint_as_float(((unsigned)h) << 16);
}

// ---------------- binning pass 1: block-local bucket sort (no global atomics) --
__global__ __launch_bounds__(256) void k_bin1(const int* __restrict__ src,
                                              const int* __restrict__ dst,
                                              int* __restrict__ tmp,
                                              int* __restrict__ counts,
                                              int* __restrict__ offsets,
                                              int NB, int NBLK, int E) {
  __shared__ int hist[128];
  __shared__ int pref[128];
  __shared__ int lofs[128];
  __shared__ int stage[CH];  // 8 KB
  const int blk = blockIdx.x;
  const int e0 = blk * CH;
  const int len = min(CH, E - e0);
  const int t = threadIdx.x;

  for (int i = t; i < 128; i += 256) hist[i] = 0;
  __syncthreads();
  int dreg[CH / 256];
#pragma unroll
  for (int it = 0; it < CH / 256; ++it) {
    int i = t + it * 256;
    if (i < len) {
      int d = dst[e0 + i];
      dreg[it] = d;
      atomicAdd(&hist[d >> BKT_SHIFT], 1);
    }
  }
  __syncthreads();
  if (t < 128) pref[t] = hist[t];
  __syncthreads();
  for (int off = 1; off < 128; off <<= 1) {
    int v = 0;
    if (t < 128 && t >= off) v = pref[t - off];
    __syncthreads();
    if (t < 128) pref[t] += v;
    __syncthreads();
  }
  if (t < NB) {
    int ex = pref[t] - hist[t];
    lofs[t] = ex;
    counts[t * NBLK + blk] = hist[t];   // [bucket][block]
    offsets[t * NBLK + blk] = ex;
  }
  __syncthreads();
#pragma unroll
  for (int it = 0; it < CH / 256; ++it) {
    int i = t + it * 256;
    if (i < len) {
      int d = dreg[it], s = src[e0 + i];
      int slot = atomicAdd(&lofs[d >> BKT_SHIFT], 1);
      stage[slot] = ((d & ((1 << BKT_SHIFT) - 1)) << SRC_BITS) | s;
    }
  }
  __syncthreads();
  int nv = len >> 2;
  for (int i = t; i < nv; i += 256) ((int4*)(tmp + e0))[i] = ((const int4*)stage)[i];
  for (int i = (nv << 2) + t; i < len; i += 256) tmp[e0 + i] = stage[i];
}

// ---------------- binning pass 2a: per-bucket degree histogram -> deg (seq) ----
__global__ __launch_bounds__(256) void k_bin2a(const int* __restrict__ tmp,
                                               const int* __restrict__ counts,
                                               const int* __restrict__ offsets,
                                               int* __restrict__ deg, int N, int NBLK) {
  __shared__ int h[1 << BKT_SHIFT];
  __shared__ int scnt[MAXBLK], soff[MAXBLK];
  const int b = blockIdx.x;
  const int t = threadIdx.x;
  const int node0 = b << BKT_SHIFT;
  for (int i = t; i < (1 << BKT_SHIFT); i += 256) h[i] = 0;
  for (int i = t; i < NBLK; i += 256) {
    scnt[i] = counts[b * NBLK + i];
    soff[i] = offsets[b * NBLK + i];
  }
  __syncthreads();
  const int lane = t & 63, w = t >> 6;
  for (int blk = w; blk < NBLK; blk += 4) {
    int cnt = scnt[blk];
    const int* p = tmp + blk * CH + soff[blk];
    for (int j = lane; j < cnt; j += 64) atomicAdd(&h[p[j] >> SRC_BITS], 1);
  }
  __syncthreads();
  for (int i = t; i < (1 << BKT_SHIFT); i += 256) {
    int n = node0 + i;
    if (n < N) deg[n] = h[i];
  }
}

// ---------------- binning pass 2b: within-bucket CSR placement ----------------
__global__ __launch_bounds__(256) void k_bin2b(const int* __restrict__ tmp,
                                               const int* __restrict__ counts,
                                               const int* __restrict__ offsets,
                                               const int* __restrict__ row_start,
                                               int* __restrict__ recs, int N, int NBLK) {
  __shared__ int lcur[1 << BKT_SHIFT];
  __shared__ int scnt[MAXBLK], soff[MAXBLK];
  const int b = blockIdx.x;
  const int t = threadIdx.x;
  const int node0 = b << BKT_SHIFT;
  for (int i = t; i < (1 << BKT_SHIFT); i += 256) {
    int n = node0 + i;
    lcur[i] = (n < N) ? row_start[n] : 0;
  }
  for (int i = t; i < NBLK; i += 256) {
    scnt[i] = counts[b * NBLK + i];
    soff[i] = offsets[b * NBLK + i];
  }
  __syncthreads();
  const int lane = t & 63, w = t >> 6;
  for (int blk = w; blk < NBLK; blk += 4) {
    int cnt = scnt[blk];
    const int* p = tmp + blk * CH + soff[blk];
    for (int j = lane; j < cnt; j += 64) {
      int rec = p[j];
      int d = rec >> SRC_BITS;
      int s = rec & ((1 << SRC_BITS) - 1);
      int slot = atomicAdd(&lcur[d], 1);
      recs[slot] = s;
    }
  }
}

// ---------------- prefix scan for row_start (+ dinv) ----------------

__global__ void k_scan1(const int* __restrict__ deg, int* __restrict__ row_start,
                        int* __restrict__ partials, float* __restrict__ dinv, int N) {
  __shared__ int sh[256];
  int t = threadIdx.x;
  int base = blockIdx.x * 1024 + t * 4;
  int v0 = 0, v1 = 0, v2 = 0, v3 = 0;
  if (base + 0 < N) v0 = deg[base + 0];
  if (base + 1 < N) v1 = deg[base + 1];
  if (base + 2 < N) v2 = deg[base + 2];
  if (base + 3 < N) v3 = deg[base + 3];
  if (base + 0 < N) dinv[base + 0] = rsqrtf((float)v0 + 1.0f);
  if (base + 1 < N) dinv[base + 1] = rsqrtf((float)v1 + 1.0f);
  if (base + 2 < N) dinv[base + 2] = rsqrtf((float)v2 + 1.0f);
  if (base + 3 < N) dinv[base + 3] = rsqrtf((float)v3 + 1.0f);
  int tsum = v0 + v1 + v2 + v3;
  sh[t] = tsum;
  __syncthreads();
  for (int off = 1; off < 256; off <<= 1) {
    int x = (t >= off) ? sh[t - off] : 0;
    __syncthreads();
    sh[t] += x;
    __syncthreads();
  }
  int excl = sh[t] - tsum;
  if (t == 255) partials[blockIdx.x] = sh[255];
  if (base + 0 < N) row_start[base + 0] = excl;
  if (base + 1 < N) row_start[base + 1] = excl + v0;
  if (base + 2 < N) row_start[base + 2] = excl + v0 + v1;
  if (base + 3 < N) row_start[base + 3] = excl + v0 + v1 + v2;
}

__global__ void k_scan2(int* partials, int nb) {  // nb <= 256
  __shared__ int sh[256];
  int t = threadIdx.x;
  int v = (t < nb) ? partials[t] : 0;
  sh[t] = v;
  __syncthreads();
  for (int off = 1; off < 256; off <<= 1) {
    int x = (t >= off) ? sh[t - off] : 0;
    __syncthreads();
    sh[t] += x;
    __syncthreads();
  }
  if (t < nb) partials[t] = sh[t] - v;  // exclusive
}

__global__ void k_scan3(int* __restrict__ row_start, const int* __restrict__ partials,
                        int N, int E) {
  int i = blockIdx.x * blockDim.x + threadIdx.x;
  if (i < N) row_start[i] += partials[i >> 10];
  if (i == 0) row_start[N] = E;
}

// ---------------- GEMM via MFMA, A direct from global ----------------
template <int K, int A_BF16>
__global__ __launch_bounds__(256) void k_gemm(const void* __restrict__ Xv,
                                              const float* __restrict__ W,
                                              unsigned short* __restrict__ Hb, int N) {
  constexpr int NKS = K / 32;
  __shared__ unsigned short sBhi[NKS * 4 * 64 * 8];
  __shared__ unsigned short sBlo[NKS * 4 * 64 * 8];
  const int tid = threadIdx.x;

  for (int idx = tid; idx < K * 64; idx += 256) {
    int k = idx >> 6, c = idx & 63;
    float wval = W[idx];
    int ks = k >> 5, r = k & 31, h2 = r >> 3, j = r & 7;
    int f = c >> 4, r16c = c & 15;
    int pos = (((ks * 4 + f) * 64) + h2 * 16 + r16c) * 8 + j;
    unsigned short hi = f2bf(wval);
    sBhi[pos] = hi;
    sBlo[pos] = f2bf(wval - bf2f(hi));
  }
  __syncthreads();

  const int lane = tid & 63;
  const int wv = tid >> 6;
  const int r16 = lane & 15;
  const int half = lane >> 4;
  const int row = blockIdx.x * 64 + wv * 16 + r16;

  f32x4 acc[4];
#pragma unroll
  for (int f = 0; f < 4; ++f) acc[f] = (f32x4){0.f, 0.f, 0.f, 0.f};

#pragma unroll
  for (int ks = 0; ks < NKS; ++ks) {
    bf16x8 ahi, alo;
    if constexpr (A_BF16) {
      union { uint4 u; bf16x8 v; } au;
      au.u = make_uint4(0, 0, 0, 0);
      if (row < N)
        au.u = *(const uint4*)((const unsigned short*)Xv + (size_t)row * K + ks * 32 + half * 8);
      ahi = au.v;
    } else {
      float4 v0 = make_float4(0.f, 0.f, 0.f, 0.f), v1 = v0;
      if (row < N) {
        const float* xp = (const float*)Xv + (size_t)row * K + ks * 32 + half * 8;
        v0 = *(const float4*)xp;
        v1 = *(const float4*)(xp + 4);
      }
      float vv[8] = {v0.x, v0.y, v0.z, v0.w, v1.x, v1.y, v1.z, v1.w};
#pragma unroll
      for (int j = 0; j < 8; ++j) {
        unsigned short h = f2bf(vv[j]);
        ahi[j] = (short)h;
        alo[j] = (short)f2bf(vv[j] - bf2f(h));
      }
    }
#pragma unroll
    for (int f = 0; f < 4; ++f) {
      bf16x8 bh = *(const bf16x8*)&sBhi[(((ks * 4 + f) * 64) + lane) * 8];
      bf16x8 bl = *(const bf16x8*)&sBlo[(((ks * 4 + f) * 64) + lane) * 8];
      acc[f] = __builtin_amdgcn_mfma_f32_16x16x32_bf16(ahi, bh, acc[f], 0, 0, 0);
      acc[f] = __builtin_amdgcn_mfma_f32_16x16x32_bf16(ahi, bl, acc[f], 0, 0, 0);
      if constexpr (!A_BF16)
        acc[f] = __builtin_amdgcn_mfma_f32_16x16x32_bf16(alo, bh, acc[f], 0, 0, 0);
    }
  }

  const int orow0 = blockIdx.x * 64 + wv * 16 + half * 4;
#pragma unroll
  for (int f = 0; f < 4; ++f) {
#pragma unroll
    for (int rg = 0; rg < 4; ++rg) {
      int orow = orow0 + rg;
      if (orow < N) Hb[(size_t)orow * HD + f * 16 + r16] = f2bf(acc[f][rg]);
    }
  }
}

// ---------------- Aggregation: bf16 gathers + f32 accumulate ----------------
template <int OUTBF16>
__global__ void k_agg(const unsigned short* __restrict__ Hb, const int* __restrict__ recs,
                      const int* __restrict__ row_start, const float* __restrict__ dinv,
                      const float* __restrict__ bias, void* __restrict__ outv, int N,
                      int relu) {
  int lane = threadIdx.x & 63;
  int node = (blockIdx.x * blockDim.x + threadIdx.x) >> 6;
  if (node >= N) return;
  float di = dinv[node];
  float acc = bf2f(Hb[(size_t)node * HD + lane]) * (di * di);
  int beg = row_start[node], end = row_start[node + 1];
  int e = beg;
  for (; e + 4 <= end; e += 4) {
    int s0 = recs[e + 0], s1 = recs[e + 1], s2 = recs[e + 2], s3 = recs[e + 3];
    float n0 = dinv[s0], n1 = dinv[s1], n2 = dinv[s2], n3 = dinv[s3];
    float h0 = bf2f(Hb[(size_t)s0 * HD + lane]);
    float h1 = bf2f(Hb[(size_t)s1 * HD + lane]);
    float h2 = bf2f(Hb[(size_t)s2 * HD + lane]);
    float h3 = bf2f(Hb[(size_t)s3 * HD + lane]);
    acc = fmaf(h0, n0 * di, acc);
    acc = fmaf(h1, n1 * di, acc);
    acc = fmaf(h2, n2 * di, acc);
    acc = fmaf(h3, n3 * di, acc);
  }
  for (; e < end; ++e) {
    int s = recs[e];
    acc = fmaf(bf2f(Hb[(size_t)s * HD + lane]), dinv[s] * di, acc);
  }
  acc += bias[lane];
  if (relu) acc = fmaxf(acc, 0.f);
  if (OUTBF16)
    ((unsigned short*)outv)[(size_t)node * HD + lane] = f2bf(acc);
  else
    ((float*)outv)[(size_t)node * HD + lane] = acc;
}

// ---------------- zscore ----------------

__global__ void k_colstats(const float* __restrict__ H, float* __restrict__ stats, int N) {
  __shared__ float ss[256], sq[256];
  int t = threadIdx.x;
  int col = t & 63, grp = t >> 6;
  float s = 0.f, q = 0.f;
  for (int row = blockIdx.x * 4 + grp; row < N; row += gridDim.x * 4) {
    float v = H[(size_t)row * HD + col];
    s += v;
    q += v * v;
  }
  ss[t] = s;
  sq[t] = q;
  __syncthreads();
  if (t < 64) {
    s = ss[t] + ss[t + 64] + ss[t + 128] + ss[t + 192];
    q = sq[t] + sq[t + 64] + sq[t + 128] + sq[t + 192];
    atomicAdd(&stats[t], s);
    atomicAdd(&stats[64 + t], q);
  }
}

__global__ void k_normalize(float* __restrict__ H, const float* __restrict__ stats, int N) {
  int i = blockIdx.x * blockDim.x + threadIdx.x;
  int total = N * HD;
  if (i >= total) return;
  int col = i & 63;
  float sum = stats[col], sumsq = stats[64 + col];
  float mean = sum / (float)N;
  float var = (sumsq - sum * sum / (float)N) / (float)(N - 1);
  float r = rsqrtf(var);
  H[i] = (H[i] - mean) * r;
}

// ---------------- launch ----------------

extern "C" void kernel_launch(void* const* d_in, const int* in_sizes, int n_in,
                              void* d_out, int out_size, void* d_ws, size_t ws_size,
                              hipStream_t stream) {
  const int IN_DIM = 256;
  const float* X[2] = {(const float*)d_in[0], (const float*)d_in[2]};
  const int* EI[2] = {(const int*)d_in[1], (const int*)d_in[3]};
  const float* W1 = (const float*)d_in[4];
  const float* b1 = (const float*)d_in[5];
  const float* W2 = (const float*)d_in[6];
  const float* b2 = (const float*)d_in[7];
  const int N = in_sizes[0] / IN_DIM;
  const int E = in_sizes[1] / 2;
  const int NB = (N + (1 << BKT_SHIFT) - 1) >> BKT_SHIFT;  // buckets (98)
  const int NBLK = (E + CH - 1) / CH;                      // bin1 blocks (782)

  char* ws = (char*)d_ws;
  size_t off = 0;
  auto carve = [&](size_t bytes) -> char* {
    char* p = ws + off;
    off += (bytes + 255) & ~(size_t)255;
    return p;
  };
  unsigned short* Hb = (unsigned short*)carve((size_t)N * HD * 2);      // gemm out (bf16)
  unsigned short* bufAgg = (unsigned short*)carve((size_t)N * HD * 2);  // agg1 out (bf16)
  int* tmp = (int*)carve((size_t)NBLK * CH * 4);
  int* recs = (int*)carve((size_t)E * 4);
  char* zero_base = carve(128 * 4);  // stats[128]
  float* stats = (float*)zero_base;
  int* deg = (int*)carve((size_t)N * 4);
  int* row_start = (int*)carve((size_t)(N + 1) * 4);
  float* dinv = (float*)carve((size_t)N * 4);
  int* partials = (int*)carve(256 * 4);
  int* counts = (int*)carve((size_t)NB * NBLK * 4);
  int* offsets = (int*)carve((size_t)NB * NBLK * 4);
  (void)ws_size; (void)n_in; (void)out_size;

  const int T = 256;
  const int gN = (N + T - 1) / T;
  const int nchunk = (N + 1023) / 1024;
  const int gWave4 = (N + 3) / 4;
  const int gGemm = (N + 63) / 64;
  const int gElem = (N * HD + T - 1) / T;

  for (int g = 0; g < 2; ++g) {
    const float* x = X[g];
    const int* src = EI[g];
    const int* dst = EI[g] + E;
    float* OUT = (float*)d_out + (size_t)g * N * HD;

    hipMemsetAsync(zero_base, 0, 128 * 4, stream);
    k_bin1<<<NBLK, T, 0, stream>>>(src, dst, tmp, counts, offsets, NB, NBLK, E);
    k_bin2a<<<NB, T, 0, stream>>>(tmp, counts, offsets, deg, N, NBLK);
    k_scan1<<<nchunk, T, 0, stream>>>(deg, row_start, partials, dinv, N);
    k_scan2<<<1, T, 0, stream>>>(partials, nchunk);
    k_scan3<<<gN, T, 0, stream>>>(row_start, partials, N, E);
    k_bin2b<<<NB, T, 0, stream>>>(tmp, counts, offsets, row_start, recs, N, NBLK);

    // layer 1: h = relu(agg(x @ W1) + b1)  [agg out bf16]
    k_gemm<256, 0><<<gGemm, T, 0, stream>>>(x, W1, Hb, N);
    k_agg<1><<<gWave4, T, 0, stream>>>(Hb, recs, row_start, dinv, b1, bufAgg, N, 1);
    // layer 2: h = agg(h1 @ W2) + b2 -> f32 straight into d_out segment
    k_gemm<64, 1><<<gGemm, T, 0, stream>>>(bufAgg, W2, Hb, N);
    k_agg<0><<<gWave4, T, 0, stream>>>(Hb, recs, row_start, dinv, b2, OUT, N, 0);

    // zscore in place on OUT
    k_colstats<<<512, T, 0, stream>>>(OUT, stats, N);
    k_normalize<<<gElem, T, 0, stream>>>(OUT, stats, N);
  }
}

// Round 8
// 634.024 us; speedup vs baseline: 1.2794x; 1.2794x over previous
//
#include <hip/hip_runtime.h>

#define HD 64        // hidden == out dim
#define CH 8192      // edges per bin1 block
#define BKT_SHIFT 10 // 1024 nodes per bucket
#define SRC_BITS 17  // N=100000 < 2^17 -> {dstlocal:10 | src:17} fits in 27 bits
#define MAXBLK 256   // >= NBLK = ceil(E/CH) = 196

typedef __attribute__((ext_vector_type(8))) short bf16x8;
typedef __attribute__((ext_vector_type(4))) float f32x4;

__device__ inline unsigned short f2bf(float x) {
  unsigned u = __float_as_uint(x);
  unsigned r = u + 0x7FFF + ((u >> 16) & 1);
  return (unsigned short)(r >> 16);
}
__device__ inline float bf2f(unsigned short h) {
  return __uint_as_float(((unsigned)h) << 16);
}

// ---------------- binning pass 1: block-local bucket sort (no global atomics) --
__global__ __launch_bounds__(256) void k_bin1(const int* __restrict__ src,
                                              const int* __restrict__ dst,
                                              int* __restrict__ tmp,
                                              int* __restrict__ counts,
                                              int* __restrict__ offsets,
                                              int NB, int NBLK, int E) {
  __shared__ int hist[128];
  __shared__ int pref[128];
  __shared__ int lofs[128];
  __shared__ int stage[CH];  // 32 KB
  const int blk = blockIdx.x;
  const int e0 = blk * CH;
  const int len = min(CH, E - e0);
  const int t = threadIdx.x;

  for (int i = t; i < 128; i += 256) hist[i] = 0;
  __syncthreads();
  int dreg[CH / 256];
#pragma unroll
  for (int it = 0; it < CH / 256; ++it) {
    int i = t + it * 256;
    if (i < len) {
      int d = dst[e0 + i];
      dreg[it] = d;
      atomicAdd(&hist[d >> BKT_SHIFT], 1);
    }
  }
  __syncthreads();
  if (t < 128) pref[t] = hist[t];
  __syncthreads();
  for (int off = 1; off < 128; off <<= 1) {
    int v = 0;
    if (t < 128 && t >= off) v = pref[t - off];
    __syncthreads();
    if (t < 128) pref[t] += v;
    __syncthreads();
  }
  if (t < NB) {
    int ex = pref[t] - hist[t];
    lofs[t] = ex;
    counts[t * NBLK + blk] = hist[t];   // [bucket][block]
    offsets[t * NBLK + blk] = ex;
  }
  __syncthreads();
#pragma unroll
  for (int it = 0; it < CH / 256; ++it) {
    int i = t + it * 256;
    if (i < len) {
      int d = dreg[it], s = src[e0 + i];
      int slot = atomicAdd(&lofs[d >> BKT_SHIFT], 1);
      stage[slot] = ((d & ((1 << BKT_SHIFT) - 1)) << SRC_BITS) | s;
    }
  }
  __syncthreads();
  int nv = len >> 2;
  for (int i = t; i < nv; i += 256) ((int4*)(tmp + e0))[i] = ((const int4*)stage)[i];
  for (int i = (nv << 2) + t; i < len; i += 256) tmp[e0 + i] = stage[i];
}

// ---------------- bucket totals + exclusive scan (one small block) ----------
__global__ __launch_bounds__(128) void k_bscan(const int* __restrict__ counts,
                                               int* __restrict__ bucket_base,
                                               int* __restrict__ row_start,
                                               int NB, int NBLK, int N, int E) {
  __shared__ int sh[128];
  int t = threadIdx.x;
  int v = 0;
  if (t < NB) {
    const int* p = counts + t * NBLK;
    for (int i = 0; i < NBLK; ++i) v += p[i];
  }
  sh[t] = v;
  __syncthreads();
  for (int off = 1; off < 128; off <<= 1) {
    int x = (t >= off) ? sh[t - off] : 0;
    __syncthreads();
    sh[t] += x;
    __syncthreads();
  }
  if (t < NB) bucket_base[t] = sh[t] - v;  // exclusive
  if (t == 0) {
    bucket_base[NB] = E;
    row_start[N] = E;
  }
}

// ---------------- merged bin2: histogram + scan + dinv/row_start + place ----
// one block (1024 thr, 16 waves) per bucket of 1024 nodes
__global__ __launch_bounds__(1024) void k_bin2m(const int* __restrict__ tmp,
                                                const int* __restrict__ counts,
                                                const int* __restrict__ offsets,
                                                const int* __restrict__ bucket_base,
                                                int* __restrict__ row_start,
                                                float* __restrict__ dinv,
                                                int* __restrict__ recs, int N, int NBLK) {
  __shared__ int h[1 << BKT_SHIFT];     // histogram -> scan -> (excl via reg)
  __shared__ int lcur[1 << BKT_SHIFT];  // place cursors
  __shared__ int scnt[MAXBLK], soff[MAXBLK];
  const int b = blockIdx.x;
  const int t = threadIdx.x;
  const int node0 = b << BKT_SHIFT;
  const int lane = t & 63, w = t >> 6;

  h[t] = 0;
  for (int i = t; i < NBLK; i += 1024) {
    scnt[i] = counts[b * NBLK + i];
    soff[i] = offsets[b * NBLK + i];
  }
  __syncthreads();
  // pass 1: histogram by local node
  for (int blk = w; blk < NBLK; blk += 16) {
    int cnt = scnt[blk];
    const int* p = tmp + blk * CH + soff[blk];
    for (int j = lane; j < cnt; j += 64) atomicAdd(&h[p[j] >> SRC_BITS], 1);
  }
  __syncthreads();
  int deg = h[t];  // my node's degree
  __syncthreads();
  // inclusive scan over 1024 bins (in-place Hillis-Steele)
  for (int off = 1; off < 1024; off <<= 1) {
    int x = (t >= off) ? h[t - off] : 0;
    __syncthreads();
    h[t] += x;
    __syncthreads();
  }
  int base = bucket_base[b] + h[t] - deg;  // global exclusive prefix for my node
  lcur[t] = base;
  int n = node0 + t;
  if (n < N) {
    row_start[n] = base;
    dinv[n] = rsqrtf((float)deg + 1.0f);
  }
  __syncthreads();
  // pass 2: place records (writes confined to this bucket's recs window)
  for (int blk = w; blk < NBLK; blk += 16) {
    int cnt = scnt[blk];
    const int* p = tmp + blk * CH + soff[blk];
    for (int j = lane; j < cnt; j += 64) {
      int rec = p[j];
      int d = rec >> SRC_BITS;
      int s = rec & ((1 << SRC_BITS) - 1);
      int slot = atomicAdd(&lcur[d], 1);
      recs[slot] = s;
    }
  }
}

// ---------------- GEMM via MFMA, A direct from global ----------------
template <int K, int A_BF16>
__global__ __launch_bounds__(256) void k_gemm(const void* __restrict__ Xv,
                                              const float* __restrict__ W,
                                              unsigned short* __restrict__ Hb, int N) {
  constexpr int NKS = K / 32;
  __shared__ unsigned short sBhi[NKS * 4 * 64 * 8];
  __shared__ unsigned short sBlo[NKS * 4 * 64 * 8];
  const int tid = threadIdx.x;

  for (int idx = tid; idx < K * 64; idx += 256) {
    int k = idx >> 6, c = idx & 63;
    float wval = W[idx];
    int ks = k >> 5, r = k & 31, h2 = r >> 3, j = r & 7;
    int f = c >> 4, r16c = c & 15;
    int pos = (((ks * 4 + f) * 64) + h2 * 16 + r16c) * 8 + j;
    unsigned short hi = f2bf(wval);
    sBhi[pos] = hi;
    sBlo[pos] = f2bf(wval - bf2f(hi));
  }
  __syncthreads();

  const int lane = tid & 63;
  const int wv = tid >> 6;
  const int r16 = lane & 15;
  const int half = lane >> 4;
  const int row = blockIdx.x * 64 + wv * 16 + r16;

  f32x4 acc[4];
#pragma unroll
  for (int f = 0; f < 4; ++f) acc[f] = (f32x4){0.f, 0.f, 0.f, 0.f};

#pragma unroll
  for (int ks = 0; ks < NKS; ++ks) {
    bf16x8 ahi, alo;
    if constexpr (A_BF16) {
      union { uint4 u; bf16x8 v; } au;
      au.u = make_uint4(0, 0, 0, 0);
      if (row < N)
        au.u = *(const uint4*)((const unsigned short*)Xv + (size_t)row * K + ks * 32 + half * 8);
      ahi = au.v;
    } else {
      float4 v0 = make_float4(0.f, 0.f, 0.f, 0.f), v1 = v0;
      if (row < N) {
        const float* xp = (const float*)Xv + (size_t)row * K + ks * 32 + half * 8;
        v0 = *(const float4*)xp;
        v1 = *(const float4*)(xp + 4);
      }
      float vv[8] = {v0.x, v0.y, v0.z, v0.w, v1.x, v1.y, v1.z, v1.w};
#pragma unroll
      for (int j = 0; j < 8; ++j) {
        unsigned short h = f2bf(vv[j]);
        ahi[j] = (short)h;
        alo[j] = (short)f2bf(vv[j] - bf2f(h));
      }
    }
#pragma unroll
    for (int f = 0; f < 4; ++f) {
      bf16x8 bh = *(const bf16x8*)&sBhi[(((ks * 4 + f) * 64) + lane) * 8];
      bf16x8 bl = *(const bf16x8*)&sBlo[(((ks * 4 + f) * 64) + lane) * 8];
      acc[f] = __builtin_amdgcn_mfma_f32_16x16x32_bf16(ahi, bh, acc[f], 0, 0, 0);
      acc[f] = __builtin_amdgcn_mfma_f32_16x16x32_bf16(ahi, bl, acc[f], 0, 0, 0);
      if constexpr (!A_BF16)
        acc[f] = __builtin_amdgcn_mfma_f32_16x16x32_bf16(alo, bh, acc[f], 0, 0, 0);
    }
  }

  const int orow0 = blockIdx.x * 64 + wv * 16 + half * 4;
#pragma unroll
  for (int f = 0; f < 4; ++f) {
#pragma unroll
    for (int rg = 0; rg < 4; ++rg) {
      int orow = orow0 + rg;
      if (orow < N) Hb[(size_t)orow * HD + f * 16 + r16] = f2bf(acc[f][rg]);
    }
  }
}

// ---------------- Aggregation: bf16 gathers + f32 accumulate ----------------
template <int OUTBF16>
__global__ void k_agg(const unsigned short* __restrict__ Hb, const int* __restrict__ recs,
                      const int* __restrict__ row_start, const float* __restrict__ dinv,
                      const float* __restrict__ bias, void* __restrict__ outv, int N,
                      int relu) {
  int lane = threadIdx.x & 63;
  int node = (blockIdx.x * blockDim.x + threadIdx.x) >> 6;
  if (node >= N) return;
  float di = dinv[node];
  float acc = bf2f(Hb[(size_t)node * HD + lane]) * (di * di);
  int beg = row_start[node], end = row_start[node + 1];
  int e = beg;
  for (; e + 4 <= end; e += 4) {
    int s0 = recs[e + 0], s1 = recs[e + 1], s2 = recs[e + 2], s3 = recs[e + 3];
    float n0 = dinv[s0], n1 = dinv[s1], n2 = dinv[s2], n3 = dinv[s3];
    float h0 = bf2f(Hb[(size_t)s0 * HD + lane]);
    float h1 = bf2f(Hb[(size_t)s1 * HD + lane]);
    float h2 = bf2f(Hb[(size_t)s2 * HD + lane]);
    float h3 = bf2f(Hb[(size_t)s3 * HD + lane]);
    acc = fmaf(h0, n0 * di, acc);
    acc = fmaf(h1, n1 * di, acc);
    acc = fmaf(h2, n2 * di, acc);
    acc = fmaf(h3, n3 * di, acc);
  }
  for (; e < end; ++e) {
    int s = recs[e];
    acc = fmaf(bf2f(Hb[(size_t)s * HD + lane]), dinv[s] * di, acc);
  }
  acc += bias[lane];
  if (relu) acc = fmaxf(acc, 0.f);
  if (OUTBF16)
    ((unsigned short*)outv)[(size_t)node * HD + lane] = f2bf(acc);
  else
    ((float*)outv)[(size_t)node * HD + lane] = acc;
}

// ---------------- zscore ----------------

__global__ void k_colstats(const float* __restrict__ H, float* __restrict__ stats, int N) {
  __shared__ float ss[256], sq[256];
  int t = threadIdx.x;
  int col = t & 63, grp = t >> 6;
  float s = 0.f, q = 0.f;
  for (int row = blockIdx.x * 4 + grp; row < N; row += gridDim.x * 4) {
    float v = H[(size_t)row * HD + col];
    s += v;
    q += v * v;
  }
  ss[t] = s;
  sq[t] = q;
  __syncthreads();
  if (t < 64) {
    s = ss[t] + ss[t + 64] + ss[t + 128] + ss[t + 192];
    q = sq[t] + sq[t + 64] + sq[t + 128] + sq[t + 192];
    atomicAdd(&stats[t], s);
    atomicAdd(&stats[64 + t], q);
  }
}

__global__ void k_normalize(float* __restrict__ H, const float* __restrict__ stats, int N) {
  int i = blockIdx.x * blockDim.x + threadIdx.x;
  int total = N * HD;
  if (i >= total) return;
  int col = i & 63;
  float sum = stats[col], sumsq = stats[64 + col];
  float mean = sum / (float)N;
  float var = (sumsq - sum * sum / (float)N) / (float)(N - 1);
  float r = rsqrtf(var);
  H[i] = (H[i] - mean) * r;
}

// ---------------- launch ----------------

extern "C" void kernel_launch(void* const* d_in, const int* in_sizes, int n_in,
                              void* d_out, int out_size, void* d_ws, size_t ws_size,
                              hipStream_t stream) {
  const int IN_DIM = 256;
  const float* X[2] = {(const float*)d_in[0], (const float*)d_in[2]};
  const int* EI[2] = {(const int*)d_in[1], (const int*)d_in[3]};
  const float* W1 = (const float*)d_in[4];
  const float* b1 = (const float*)d_in[5];
  const float* W2 = (const float*)d_in[6];
  const float* b2 = (const float*)d_in[7];
  const int N = in_sizes[0] / IN_DIM;
  const int E = in_sizes[1] / 2;
  const int NB = (N + (1 << BKT_SHIFT) - 1) >> BKT_SHIFT;  // buckets (98)
  const int NBLK = (E + CH - 1) / CH;                      // bin1 blocks (196)

  char* ws = (char*)d_ws;
  size_t off = 0;
  auto carve = [&](size_t bytes) -> char* {
    char* p = ws + off;
    off += (bytes + 255) & ~(size_t)255;
    return p;
  };
  unsigned short* Hb = (unsigned short*)carve((size_t)N * HD * 2);      // gemm out (bf16)
  unsigned short* bufAgg = (unsigned short*)carve((size_t)N * HD * 2);  // agg1 out (bf16)
  int* tmp = (int*)carve((size_t)NBLK * CH * 4);
  int* recs = (int*)carve((size_t)E * 4);
  char* zero_base = carve(128 * 4);  // stats[128]
  float* stats = (float*)zero_base;
  int* row_start = (int*)carve((size_t)(N + 1) * 4);
  float* dinv = (float*)carve((size_t)N * 4);
  int* bucket_base = (int*)carve((size_t)(NB + 1) * 4);
  int* counts = (int*)carve((size_t)NB * NBLK * 4);
  int* offsets = (int*)carve((size_t)NB * NBLK * 4);
  (void)ws_size; (void)n_in; (void)out_size;

  const int T = 256;
  const int gWave4 = (N + 3) / 4;
  const int gGemm = (N + 63) / 64;
  const int gElem = (N * HD + T - 1) / T;

  for (int g = 0; g < 2; ++g) {
    const float* x = X[g];
    const int* src = EI[g];
    const int* dst = EI[g] + E;
    float* OUT = (float*)d_out + (size_t)g * N * HD;

    hipMemsetAsync(zero_base, 0, 128 * 4, stream);
    k_bin1<<<NBLK, T, 0, stream>>>(src, dst, tmp, counts, offsets, NB, NBLK, E);
    k_bscan<<<1, 128, 0, stream>>>(counts, bucket_base, row_start, NB, NBLK, N, E);
    k_bin2m<<<NB, 1024, 0, stream>>>(tmp, counts, offsets, bucket_base, row_start, dinv,
                                     recs, N, NBLK);

    // layer 1: h = relu(agg(x @ W1) + b1)  [agg out bf16]
    k_gemm<256, 0><<<gGemm, T, 0, stream>>>(x, W1, Hb, N);
    k_agg<1><<<gWave4, T, 0, stream>>>(Hb, recs, row_start, dinv, b1, bufAgg, N, 1);
    // layer 2: h = agg(h1 @ W2) + b2 -> f32 straight into d_out segment
    k_gemm<64, 1><<<gGemm, T, 0, stream>>>(bufAgg, W2, Hb, N);
    k_agg<0><<<gWave4, T, 0, stream>>>(Hb, recs, row_start, dinv, b2, OUT, N, 0);

    // zscore in place on OUT
    k_colstats<<<512, T, 0, stream>>>(OUT, stats, N);
    k_normalize<<<gElem, T, 0, stream>>>(OUT, stats, N);
  }
}

// Round 9
// 593.578 us; speedup vs baseline: 1.3666x; 1.0681x over previous
//
#include <hip/hip_runtime.h>

#define HD 64        // hidden == out dim
#define CH 8192      // edges per bin1 block
#define BKT_SHIFT 10 // 1024 nodes per bucket
#define SRC_BITS 17  // N=100000 < 2^17 -> {dstlocal:10 | src:17} fits in 27 bits
#define MAXBLK 256   // >= NBLK = ceil(E/CH) = 196

typedef __attribute__((ext_vector_type(8))) short bf16x8;
typedef __attribute__((ext_vector_type(4))) float f32x4;

__device__ inline unsigned short f2bf(float x) {
  unsigned u = __float_as_uint(x);
  unsigned r = u + 0x7FFF + ((u >> 16) & 1);
  return (unsigned short)(r >> 16);
}
__device__ inline float bf2f(unsigned short h) {
  return __uint_as_float(((unsigned)h) << 16);
}

// ---------------- binning pass 1: block-local bucket sort (no global atomics) --
__global__ __launch_bounds__(256) void k_bin1(const int* __restrict__ src,
                                              const int* __restrict__ dst,
                                              int* __restrict__ tmp,
                                              int* __restrict__ counts,
                                              int* __restrict__ offsets,
                                              int NB, int NBLK, int E) {
  __shared__ int hist[128];
  __shared__ int pref[128];
  __shared__ int lofs[128];
  __shared__ int stage[CH];  // 32 KB
  const int blk = blockIdx.x;
  const int e0 = blk * CH;
  const int len = min(CH, E - e0);
  const int t = threadIdx.x;

  for (int i = t; i < 128; i += 256) hist[i] = 0;
  __syncthreads();
  int dreg[CH / 256];
#pragma unroll
  for (int it = 0; it < CH / 256; ++it) {
    int i = t + it * 256;
    if (i < len) {
      int d = dst[e0 + i];
      dreg[it] = d;
      atomicAdd(&hist[d >> BKT_SHIFT], 1);
    }
  }
  __syncthreads();
  if (t < 128) pref[t] = hist[t];
  __syncthreads();
  for (int off = 1; off < 128; off <<= 1) {
    int v = 0;
    if (t < 128 && t >= off) v = pref[t - off];
    __syncthreads();
    if (t < 128) pref[t] += v;
    __syncthreads();
  }
  if (t < NB) {
    int ex = pref[t] - hist[t];
    lofs[t] = ex;
    counts[t * NBLK + blk] = hist[t];   // [bucket][block]
    offsets[t * NBLK + blk] = ex;
  }
  __syncthreads();
#pragma unroll
  for (int it = 0; it < CH / 256; ++it) {
    int i = t + it * 256;
    if (i < len) {
      int d = dreg[it], s = src[e0 + i];
      int slot = atomicAdd(&lofs[d >> BKT_SHIFT], 1);
      stage[slot] = ((d & ((1 << BKT_SHIFT) - 1)) << SRC_BITS) | s;
    }
  }
  __syncthreads();
  int nv = len >> 2;
  for (int i = t; i < nv; i += 256) ((int4*)(tmp + e0))[i] = ((const int4*)stage)[i];
  for (int i = (nv << 2) + t; i < len; i += 256) tmp[e0 + i] = stage[i];
}

// ---------------- bucket totals + exclusive scan (one small block) ----------
__global__ __launch_bounds__(128) void k_bscan(const int* __restrict__ counts,
                                               int* __restrict__ bucket_base,
                                               int* __restrict__ row_start,
                                               int NB, int NBLK, int N, int E) {
  __shared__ int sh[128];
  int t = threadIdx.x;
  int v = 0;
  if (t < NB) {
    const int* p = counts + t * NBLK;
    for (int i = 0; i < NBLK; ++i) v += p[i];
  }
  sh[t] = v;
  __syncthreads();
  for (int off = 1; off < 128; off <<= 1) {
    int x = (t >= off) ? sh[t - off] : 0;
    __syncthreads();
    sh[t] += x;
    __syncthreads();
  }
  if (t < NB) bucket_base[t] = sh[t] - v;  // exclusive
  if (t == 0) {
    bucket_base[NB] = E;
    row_start[N] = E;
  }
}

// ---------------- merged bin2: histogram + scan + dinv/row_start + place ----
// one block (1024 thr, 16 waves) per bucket of 1024 nodes
__global__ __launch_bounds__(1024) void k_bin2m(const int* __restrict__ tmp,
                                                const int* __restrict__ counts,
                                                const int* __restrict__ offsets,
                                                const int* __restrict__ bucket_base,
                                                int* __restrict__ row_start,
                                                float* __restrict__ dinv,
                                                int* __restrict__ recs, int N, int NBLK) {
  __shared__ int h[1 << BKT_SHIFT];     // histogram -> scan -> (excl via reg)
  __shared__ int lcur[1 << BKT_SHIFT];  // place cursors
  __shared__ int scnt[MAXBLK], soff[MAXBLK];
  const int b = blockIdx.x;
  const int t = threadIdx.x;
  const int node0 = b << BKT_SHIFT;
  const int lane = t & 63, w = t >> 6;

  h[t] = 0;
  for (int i = t; i < NBLK; i += 1024) {
    scnt[i] = counts[b * NBLK + i];
    soff[i] = offsets[b * NBLK + i];
  }
  __syncthreads();
  // pass 1: histogram by local node
  for (int blk = w; blk < NBLK; blk += 16) {
    int cnt = scnt[blk];
    const int* p = tmp + blk * CH + soff[blk];
    for (int j = lane; j < cnt; j += 64) atomicAdd(&h[p[j] >> SRC_BITS], 1);
  }
  __syncthreads();
  int deg = h[t];  // my node's degree
  __syncthreads();
  // inclusive scan over 1024 bins (in-place Hillis-Steele)
  for (int off = 1; off < 1024; off <<= 1) {
    int x = (t >= off) ? h[t - off] : 0;
    __syncthreads();
    h[t] += x;
    __syncthreads();
  }
  int base = bucket_base[b] + h[t] - deg;  // global exclusive prefix for my node
  lcur[t] = base;
  int n = node0 + t;
  if (n < N) {
    row_start[n] = base;
    dinv[n] = rsqrtf((float)deg + 1.0f);
  }
  __syncthreads();
  // pass 2: place records (writes confined to this bucket's recs window)
  for (int blk = w; blk < NBLK; blk += 16) {
    int cnt = scnt[blk];
    const int* p = tmp + blk * CH + soff[blk];
    for (int j = lane; j < cnt; j += 64) {
      int rec = p[j];
      int d = rec >> SRC_BITS;
      int s = rec & ((1 << SRC_BITS) - 1);
      int slot = atomicAdd(&lcur[d], 1);
      recs[slot] = s;
    }
  }
}

// ---------------- GEMM via MFMA, A direct from global ----------------
// 512 threads = 8 waves, 128 rows/block; full B pre-swizzled in LDS.
template <int K, int A_BF16>
__global__ __launch_bounds__(512, 4) void k_gemm(const void* __restrict__ Xv,
                                                 const float* __restrict__ W,
                                                 unsigned short* __restrict__ Hb, int N) {
  constexpr int NKS = K / 32;
  __shared__ unsigned short sBhi[NKS * 4 * 64 * 8];
  __shared__ unsigned short sBlo[NKS * 4 * 64 * 8];
  const int tid = threadIdx.x;

  for (int idx = tid; idx < K * 64; idx += 512) {
    int k = idx >> 6, c = idx & 63;
    float wval = W[idx];
    int ks = k >> 5, r = k & 31, h2 = r >> 3, j = r & 7;
    int f = c >> 4, r16c = c & 15;
    int pos = (((ks * 4 + f) * 64) + h2 * 16 + r16c) * 8 + j;
    unsigned short hi = f2bf(wval);
    sBhi[pos] = hi;
    sBlo[pos] = f2bf(wval - bf2f(hi));
  }
  __syncthreads();

  const int lane = tid & 63;
  const int wv = tid >> 6;  // 0..7
  const int r16 = lane & 15;
  const int half = lane >> 4;
  const int row = blockIdx.x * 128 + wv * 16 + r16;

  f32x4 acc[4];
#pragma unroll
  for (int f = 0; f < 4; ++f) acc[f] = (f32x4){0.f, 0.f, 0.f, 0.f};

#pragma unroll
  for (int ks = 0; ks < NKS; ++ks) {
    bf16x8 ahi, alo;
    if constexpr (A_BF16) {
      union { uint4 u; bf16x8 v; } au;
      au.u = make_uint4(0, 0, 0, 0);
      if (row < N)
        au.u = *(const uint4*)((const unsigned short*)Xv + (size_t)row * K + ks * 32 + half * 8);
      ahi = au.v;
    } else {
      float4 v0 = make_float4(0.f, 0.f, 0.f, 0.f), v1 = v0;
      if (row < N) {
        const float* xp = (const float*)Xv + (size_t)row * K + ks * 32 + half * 8;
        v0 = *(const float4*)xp;
        v1 = *(const float4*)(xp + 4);
      }
      float vv[8] = {v0.x, v0.y, v0.z, v0.w, v1.x, v1.y, v1.z, v1.w};
#pragma unroll
      for (int j = 0; j < 8; ++j) {
        unsigned short h = f2bf(vv[j]);
        ahi[j] = (short)h;
        alo[j] = (short)f2bf(vv[j] - bf2f(h));
      }
    }
#pragma unroll
    for (int f = 0; f < 4; ++f) {
      bf16x8 bh = *(const bf16x8*)&sBhi[(((ks * 4 + f) * 64) + lane) * 8];
      bf16x8 bl = *(const bf16x8*)&sBlo[(((ks * 4 + f) * 64) + lane) * 8];
      acc[f] = __builtin_amdgcn_mfma_f32_16x16x32_bf16(ahi, bh, acc[f], 0, 0, 0);
      acc[f] = __builtin_amdgcn_mfma_f32_16x16x32_bf16(ahi, bl, acc[f], 0, 0, 0);
      if constexpr (!A_BF16)
        acc[f] = __builtin_amdgcn_mfma_f32_16x16x32_bf16(alo, bh, acc[f], 0, 0, 0);
    }
  }

  const int orow0 = blockIdx.x * 128 + wv * 16 + half * 4;
#pragma unroll
  for (int f = 0; f < 4; ++f) {
#pragma unroll
    for (int rg = 0; rg < 4; ++rg) {
      int orow = orow0 + rg;
      if (orow < N) Hb[(size_t)orow * HD + f * 16 + r16] = f2bf(acc[f][rg]);
    }
  }
}

// ---------------- Aggregation: bf16 gathers + f32 accumulate ----------------
template <int OUTBF16>
__global__ void k_agg(const unsigned short* __restrict__ Hb, const int* __restrict__ recs,
                      const int* __restrict__ row_start, const float* __restrict__ dinv,
                      const float* __restrict__ bias, void* __restrict__ outv, int N,
                      int relu) {
  int lane = threadIdx.x & 63;
  int node = (blockIdx.x * blockDim.x + threadIdx.x) >> 6;
  if (node >= N) return;
  float di = dinv[node];
  float acc = bf2f(Hb[(size_t)node * HD + lane]) * (di * di);
  int beg = row_start[node], end = row_start[node + 1];
  int e = beg;
  for (; e + 4 <= end; e += 4) {
    int s0 = recs[e + 0], s1 = recs[e + 1], s2 = recs[e + 2], s3 = recs[e + 3];
    float n0 = dinv[s0], n1 = dinv[s1], n2 = dinv[s2], n3 = dinv[s3];
    float h0 = bf2f(Hb[(size_t)s0 * HD + lane]);
    float h1 = bf2f(Hb[(size_t)s1 * HD + lane]);
    float h2 = bf2f(Hb[(size_t)s2 * HD + lane]);
    float h3 = bf2f(Hb[(size_t)s3 * HD + lane]);
    acc = fmaf(h0, n0 * di, acc);
    acc = fmaf(h1, n1 * di, acc);
    acc = fmaf(h2, n2 * di, acc);
    acc = fmaf(h3, n3 * di, acc);
  }
  for (; e < end; ++e) {
    int s = recs[e];
    acc = fmaf(bf2f(Hb[(size_t)s * HD + lane]), dinv[s] * di, acc);
  }
  acc += bias[lane];
  if (relu) acc = fmaxf(acc, 0.f);
  if (OUTBF16)
    ((unsigned short*)outv)[(size_t)node * HD + lane] = f2bf(acc);
  else
    ((float*)outv)[(size_t)node * HD + lane] = acc;
}

// ---------------- zscore ----------------

__global__ void k_colstats(const float* __restrict__ H, float* __restrict__ stats, int N) {
  __shared__ float ss[256], sq[256];
  int t = threadIdx.x;
  int col = t & 63, grp = t >> 6;
  float s = 0.f, q = 0.f;
  for (int row = blockIdx.x * 4 + grp; row < N; row += gridDim.x * 4) {
    float v = H[(size_t)row * HD + col];
    s += v;
    q += v * v;
  }
  ss[t] = s;
  sq[t] = q;
  __syncthreads();
  if (t < 64) {
    s = ss[t] + ss[t + 64] + ss[t + 128] + ss[t + 192];
    q = sq[t] + sq[t + 64] + sq[t + 128] + sq[t + 192];
    atomicAdd(&stats[t], s);
    atomicAdd(&stats[64 + t], q);
  }
}

__global__ void k_normalize(float* __restrict__ H, const float* __restrict__ stats, int N) {
  int i = blockIdx.x * blockDim.x + threadIdx.x;
  int total = N * HD;
  if (i >= total) return;
  int col = i & 63;
  float sum = stats[col], sumsq = stats[64 + col];
  float mean = sum / (float)N;
  float var = (sumsq - sum * sum / (float)N) / (float)(N - 1);
  float r = rsqrtf(var);
  H[i] = (H[i] - mean) * r;
}

// ---------------- launch ----------------

extern "C" void kernel_launch(void* const* d_in, const int* in_sizes, int n_in,
                              void* d_out, int out_size, void* d_ws, size_t ws_size,
                              hipStream_t stream) {
  const int IN_DIM = 256;
  const float* X[2] = {(const float*)d_in[0], (const float*)d_in[2]};
  const int* EI[2] = {(const int*)d_in[1], (const int*)d_in[3]};
  const float* W1 = (const float*)d_in[4];
  const float* b1 = (const float*)d_in[5];
  const float* W2 = (const float*)d_in[6];
  const float* b2 = (const float*)d_in[7];
  const int N = in_sizes[0] / IN_DIM;
  const int E = in_sizes[1] / 2;
  const int NB = (N + (1 << BKT_SHIFT) - 1) >> BKT_SHIFT;  // buckets (98)
  const int NBLK = (E + CH - 1) / CH;                      // bin1 blocks (196)

  char* ws = (char*)d_ws;
  size_t off = 0;
  auto carve = [&](size_t bytes) -> char* {
    char* p = ws + off;
    off += (bytes + 255) & ~(size_t)255;
    return p;
  };
  unsigned short* Hb = (unsigned short*)carve((size_t)N * HD * 2);      // gemm out (bf16)
  unsigned short* bufAgg = (unsigned short*)carve((size_t)N * HD * 2);  // agg1 out (bf16)
  int* tmp = (int*)carve((size_t)NBLK * CH * 4);
  int* recs = (int*)carve((size_t)E * 4);
  char* zero_base = carve(128 * 4);  // stats[128]
  float* stats = (float*)zero_base;
  int* row_start = (int*)carve((size_t)(N + 1) * 4);
  float* dinv = (float*)carve((size_t)N * 4);
  int* bucket_base = (int*)carve((size_t)(NB + 1) * 4);
  int* counts = (int*)carve((size_t)NB * NBLK * 4);
  int* offsets = (int*)carve((size_t)NB * NBLK * 4);
  (void)ws_size; (void)n_in; (void)out_size;

  const int T = 256;
  const int gWave4 = (N + 3) / 4;
  const int gGemm = (N + 127) / 128;  // 128 rows per block
  const int gElem = (N * HD + T - 1) / T;

  for (int g = 0; g < 2; ++g) {
    const float* x = X[g];
    const int* src = EI[g];
    const int* dst = EI[g] + E;
    float* OUT = (float*)d_out + (size_t)g * N * HD;

    hipMemsetAsync(zero_base, 0, 128 * 4, stream);
    k_bin1<<<NBLK, T, 0, stream>>>(src, dst, tmp, counts, offsets, NB, NBLK, E);
    k_bscan<<<1, 128, 0, stream>>>(counts, bucket_base, row_start, NB, NBLK, N, E);
    k_bin2m<<<NB, 1024, 0, stream>>>(tmp, counts, offsets, bucket_base, row_start, dinv,
                                     recs, N, NBLK);

    // layer 1: h = relu(agg(x @ W1) + b1)  [agg out bf16]
    k_gemm<256, 0><<<gGemm, 512, 0, stream>>>(x, W1, Hb, N);
    k_agg<1><<<gWave4, T, 0, stream>>>(Hb, recs, row_start, dinv, b1, bufAgg, N, 1);
    // layer 2: h = agg(h1 @ W2) + b2 -> f32 straight into d_out segment
    k_gemm<64, 1><<<gGemm, 512, 0, stream>>>(bufAgg, W2, Hb, N);
    k_agg<0><<<gWave4, T, 0, stream>>>(Hb, recs, row_start, dinv, b2, OUT, N, 0);

    // zscore in place on OUT
    k_colstats<<<512, T, 0, stream>>>(OUT, stats, N);
    k_normalize<<<gElem, T, 0, stream>>>(OUT, stats, N);
  }
}

// Round 10
// 477.058 us; speedup vs baseline: 1.7004x; 1.2442x over previous
//
#include <hip/hip_runtime.h>

#define HD 64        // hidden == out dim
#define CH 8192      // edges per bin1 block
#define BKT_SHIFT 10 // 1024 nodes per bucket
#define SRC_BITS 17  // N=100000 < 2^17 -> {dstlocal:10 | src:17} fits in 27 bits
#define MAXBLK 256   // >= NBLK = ceil(E/CH) = 196

typedef __attribute__((ext_vector_type(8))) short bf16x8;
typedef __attribute__((ext_vector_type(4))) float f32x4;

__device__ inline unsigned short f2bf(float x) {
  unsigned u = __float_as_uint(x);
  unsigned r = u + 0x7FFF + ((u >> 16) & 1);
  return (unsigned short)(r >> 16);
}
__device__ inline float bf2f(unsigned short h) {
  return __uint_as_float(((unsigned)h) << 16);
}

// ---------------- binning pass 1: block-local bucket sort (no global atomics) --
__global__ __launch_bounds__(256) void k_bin1(const int* __restrict__ src,
                                              const int* __restrict__ dst,
                                              int* __restrict__ tmp,
                                              int* __restrict__ counts,
                                              int* __restrict__ offsets,
                                              int NB, int NBLK, int E) {
  __shared__ int hist[128];
  __shared__ int pref[128];
  __shared__ int lofs[128];
  __shared__ int stage[CH];  // 32 KB
  const int blk = blockIdx.x;
  const int e0 = blk * CH;
  const int len = min(CH, E - e0);
  const int t = threadIdx.x;

  for (int i = t; i < 128; i += 256) hist[i] = 0;
  __syncthreads();
  int dreg[CH / 256];
#pragma unroll
  for (int it = 0; it < CH / 256; ++it) {
    int i = t + it * 256;
    if (i < len) {
      int d = dst[e0 + i];
      dreg[it] = d;
      atomicAdd(&hist[d >> BKT_SHIFT], 1);
    }
  }
  __syncthreads();
  if (t < 128) pref[t] = hist[t];
  __syncthreads();
  for (int off = 1; off < 128; off <<= 1) {
    int v = 0;
    if (t < 128 && t >= off) v = pref[t - off];
    __syncthreads();
    if (t < 128) pref[t] += v;
    __syncthreads();
  }
  if (t < NB) {
    int ex = pref[t] - hist[t];
    lofs[t] = ex;
    counts[t * NBLK + blk] = hist[t];   // [bucket][block]
    offsets[t * NBLK + blk] = ex;
  }
  __syncthreads();
#pragma unroll
  for (int it = 0; it < CH / 256; ++it) {
    int i = t + it * 256;
    if (i < len) {
      int d = dreg[it], s = src[e0 + i];
      int slot = atomicAdd(&lofs[d >> BKT_SHIFT], 1);
      stage[slot] = ((d & ((1 << BKT_SHIFT) - 1)) << SRC_BITS) | s;
    }
  }
  __syncthreads();
  int nv = len >> 2;
  for (int i = t; i < nv; i += 256) ((int4*)(tmp + e0))[i] = ((const int4*)stage)[i];
  for (int i = (nv << 2) + t; i < len; i += 256) tmp[e0 + i] = stage[i];
}

// ---------------- bucket totals + exclusive scan (one small block) ----------
__global__ __launch_bounds__(128) void k_bscan(const int* __restrict__ counts,
                                               int* __restrict__ bucket_base,
                                               int* __restrict__ row_start,
                                               int NB, int NBLK, int N, int E) {
  __shared__ int sh[128];
  int t = threadIdx.x;
  int v = 0;
  if (t < NB) {
    const int* p = counts + t * NBLK;
    for (int i = 0; i < NBLK; ++i) v += p[i];
  }
  sh[t] = v;
  __syncthreads();
  for (int off = 1; off < 128; off <<= 1) {
    int x = (t >= off) ? sh[t - off] : 0;
    __syncthreads();
    sh[t] += x;
    __syncthreads();
  }
  if (t < NB) bucket_base[t] = sh[t] - v;  // exclusive
  if (t == 0) {
    bucket_base[NB] = E;
    row_start[N] = E;
  }
}

// ---------------- merged bin2: histogram + scan + dinv/row_start + place ----
// one block (1024 thr, 16 waves) per bucket of 1024 nodes
__global__ __launch_bounds__(1024) void k_bin2m(const int* __restrict__ tmp,
                                                const int* __restrict__ counts,
                                                const int* __restrict__ offsets,
                                                const int* __restrict__ bucket_base,
                                                int* __restrict__ row_start,
                                                float* __restrict__ dinv,
                                                int* __restrict__ recs, int N, int NBLK) {
  __shared__ int h[1 << BKT_SHIFT];     // histogram -> scan -> (excl via reg)
  __shared__ int lcur[1 << BKT_SHIFT];  // place cursors
  __shared__ int scnt[MAXBLK], soff[MAXBLK];
  const int b = blockIdx.x;
  const int t = threadIdx.x;
  const int node0 = b << BKT_SHIFT;
  const int lane = t & 63, w = t >> 6;

  h[t] = 0;
  for (int i = t; i < NBLK; i += 1024) {
    scnt[i] = counts[b * NBLK + i];
    soff[i] = offsets[b * NBLK + i];
  }
  __syncthreads();
  // pass 1: histogram by local node
  for (int blk = w; blk < NBLK; blk += 16) {
    int cnt = scnt[blk];
    const int* p = tmp + blk * CH + soff[blk];
    for (int j = lane; j < cnt; j += 64) atomicAdd(&h[p[j] >> SRC_BITS], 1);
  }
  __syncthreads();
  int deg = h[t];  // my node's degree
  __syncthreads();
  // inclusive scan over 1024 bins (in-place Hillis-Steele)
  for (int off = 1; off < 1024; off <<= 1) {
    int x = (t >= off) ? h[t - off] : 0;
    __syncthreads();
    h[t] += x;
    __syncthreads();
  }
  int base = bucket_base[b] + h[t] - deg;  // global exclusive prefix for my node
  lcur[t] = base;
  int n = node0 + t;
  if (n < N) {
    row_start[n] = base;
    dinv[n] = rsqrtf((float)deg + 1.0f);
  }
  __syncthreads();
  // pass 2: place records (writes confined to this bucket's recs window)
  for (int blk = w; blk < NBLK; blk += 16) {
    int cnt = scnt[blk];
    const int* p = tmp + blk * CH + soff[blk];
    for (int j = lane; j < cnt; j += 64) {
      int rec = p[j];
      int d = rec >> SRC_BITS;
      int s = rec & ((1 << SRC_BITS) - 1);
      int slot = atomicAdd(&lcur[d], 1);
      recs[slot] = s;
    }
  }
}

// ---------------- GEMM via MFMA, A direct from global ----------------
// 512 threads = 8 waves, 128 rows/block; full B pre-swizzled in LDS.
template <int K, int A_BF16>
__global__ __launch_bounds__(512, 4) void k_gemm(const void* __restrict__ Xv,
                                                 const float* __restrict__ W,
                                                 unsigned short* __restrict__ Hb, int N) {
  constexpr int NKS = K / 32;
  __shared__ unsigned short sBhi[NKS * 4 * 64 * 8];
  __shared__ unsigned short sBlo[NKS * 4 * 64 * 8];
  const int tid = threadIdx.x;

  for (int idx = tid; idx < K * 64; idx += 512) {
    int k = idx >> 6, c = idx & 63;
    float wval = W[idx];
    int ks = k >> 5, r = k & 31, h2 = r >> 3, j = r & 7;
    int f = c >> 4, r16c = c & 15;
    int pos = (((ks * 4 + f) * 64) + h2 * 16 + r16c) * 8 + j;
    unsigned short hi = f2bf(wval);
    sBhi[pos] = hi;
    sBlo[pos] = f2bf(wval - bf2f(hi));
  }
  __syncthreads();

  const int lane = tid & 63;
  const int wv = tid >> 6;  // 0..7
  const int r16 = lane & 15;
  const int half = lane >> 4;
  const int row = blockIdx.x * 128 + wv * 16 + r16;

  f32x4 acc[4];
#pragma unroll
  for (int f = 0; f < 4; ++f) acc[f] = (f32x4){0.f, 0.f, 0.f, 0.f};

#pragma unroll
  for (int ks = 0; ks < NKS; ++ks) {
    bf16x8 ahi, alo;
    if constexpr (A_BF16) {
      union { uint4 u; bf16x8 v; } au;
      au.u = make_uint4(0, 0, 0, 0);
      if (row < N)
        au.u = *(const uint4*)((const unsigned short*)Xv + (size_t)row * K + ks * 32 + half * 8);
      ahi = au.v;
    } else {
      float4 v0 = make_float4(0.f, 0.f, 0.f, 0.f), v1 = v0;
      if (row < N) {
        const float* xp = (const float*)Xv + (size_t)row * K + ks * 32 + half * 8;
        v0 = *(const float4*)xp;
        v1 = *(const float4*)(xp + 4);
      }
      float vv[8] = {v0.x, v0.y, v0.z, v0.w, v1.x, v1.y, v1.z, v1.w};
#pragma unroll
      for (int j = 0; j < 8; ++j) {
        unsigned short h = f2bf(vv[j]);
        ahi[j] = (short)h;
        alo[j] = (short)f2bf(vv[j] - bf2f(h));
      }
    }
#pragma unroll
    for (int f = 0; f < 4; ++f) {
      bf16x8 bh = *(const bf16x8*)&sBhi[(((ks * 4 + f) * 64) + lane) * 8];
      bf16x8 bl = *(const bf16x8*)&sBlo[(((ks * 4 + f) * 64) + lane) * 8];
      acc[f] = __builtin_amdgcn_mfma_f32_16x16x32_bf16(ahi, bh, acc[f], 0, 0, 0);
      acc[f] = __builtin_amdgcn_mfma_f32_16x16x32_bf16(ahi, bl, acc[f], 0, 0, 0);
      if constexpr (!A_BF16)
        acc[f] = __builtin_amdgcn_mfma_f32_16x16x32_bf16(alo, bh, acc[f], 0, 0, 0);
    }
  }

  const int orow0 = blockIdx.x * 128 + wv * 16 + half * 4;
#pragma unroll
  for (int f = 0; f < 4; ++f) {
#pragma unroll
    for (int rg = 0; rg < 4; ++rg) {
      int orow = orow0 + rg;
      if (orow < N) Hb[(size_t)orow * HD + f * 16 + r16] = f2bf(acc[f][rg]);
    }
  }
}

// ---------------- Aggregation: 4 nodes/wave, 16 lanes/node, uint2 gathers ----
// lane16 covers channels [lane16*4, lane16*4+4); 4 independent edge streams
// per wave x 4-deep unroll = 16 outstanding 128B gathers.
template <int OUTBF16>
__global__ __launch_bounds__(256) void k_agg(const unsigned short* __restrict__ Hb,
                                             const int* __restrict__ recs,
                                             const int* __restrict__ row_start,
                                             const float* __restrict__ dinv,
                                             const float* __restrict__ bias,
                                             void* __restrict__ outv, int N, int relu) {
  const int t = threadIdx.x;
  const int node = (blockIdx.x * blockDim.x + t) >> 4;
  const int lane16 = t & 15;
  if (node >= N) return;
  const int c0 = lane16 * 4;
  float di = dinv[node];
  float a0, a1, a2, a3;
  {
    uint2 h = *(const uint2*)&Hb[(size_t)node * HD + c0];
    float dd = di * di;
    a0 = bf2f((unsigned short)(h.x & 0xffff)) * dd;
    a1 = bf2f((unsigned short)(h.x >> 16)) * dd;
    a2 = bf2f((unsigned short)(h.y & 0xffff)) * dd;
    a3 = bf2f((unsigned short)(h.y >> 16)) * dd;
  }
  const int beg = row_start[node], end = row_start[node + 1];
  int e = beg;
  for (; e + 4 <= end; e += 4) {
    int s0 = recs[e + 0], s1 = recs[e + 1], s2 = recs[e + 2], s3 = recs[e + 3];
    uint2 g0 = *(const uint2*)&Hb[(size_t)s0 * HD + c0];
    uint2 g1 = *(const uint2*)&Hb[(size_t)s1 * HD + c0];
    uint2 g2 = *(const uint2*)&Hb[(size_t)s2 * HD + c0];
    uint2 g3 = *(const uint2*)&Hb[(size_t)s3 * HD + c0];
    float n0 = dinv[s0] * di, n1 = dinv[s1] * di, n2 = dinv[s2] * di, n3 = dinv[s3] * di;
    a0 = fmaf(bf2f((unsigned short)(g0.x & 0xffff)), n0, a0);
    a1 = fmaf(bf2f((unsigned short)(g0.x >> 16)), n0, a1);
    a2 = fmaf(bf2f((unsigned short)(g0.y & 0xffff)), n0, a2);
    a3 = fmaf(bf2f((unsigned short)(g0.y >> 16)), n0, a3);
    a0 = fmaf(bf2f((unsigned short)(g1.x & 0xffff)), n1, a0);
    a1 = fmaf(bf2f((unsigned short)(g1.x >> 16)), n1, a1);
    a2 = fmaf(bf2f((unsigned short)(g1.y & 0xffff)), n1, a2);
    a3 = fmaf(bf2f((unsigned short)(g1.y >> 16)), n1, a3);
    a0 = fmaf(bf2f((unsigned short)(g2.x & 0xffff)), n2, a0);
    a1 = fmaf(bf2f((unsigned short)(g2.x >> 16)), n2, a1);
    a2 = fmaf(bf2f((unsigned short)(g2.y & 0xffff)), n2, a2);
    a3 = fmaf(bf2f((unsigned short)(g2.y >> 16)), n2, a3);
    a0 = fmaf(bf2f((unsigned short)(g3.x & 0xffff)), n3, a0);
    a1 = fmaf(bf2f((unsigned short)(g3.x >> 16)), n3, a1);
    a2 = fmaf(bf2f((unsigned short)(g3.y & 0xffff)), n3, a2);
    a3 = fmaf(bf2f((unsigned short)(g3.y >> 16)), n3, a3);
  }
  for (; e < end; ++e) {
    int s = recs[e];
    uint2 g = *(const uint2*)&Hb[(size_t)s * HD + c0];
    float n = dinv[s] * di;
    a0 = fmaf(bf2f((unsigned short)(g.x & 0xffff)), n, a0);
    a1 = fmaf(bf2f((unsigned short)(g.x >> 16)), n, a1);
    a2 = fmaf(bf2f((unsigned short)(g.y & 0xffff)), n, a2);
    a3 = fmaf(bf2f((unsigned short)(g.y >> 16)), n, a3);
  }
  float4 bv = *(const float4*)&bias[c0];
  a0 += bv.x; a1 += bv.y; a2 += bv.z; a3 += bv.w;
  if (relu) {
    a0 = fmaxf(a0, 0.f); a1 = fmaxf(a1, 0.f);
    a2 = fmaxf(a2, 0.f); a3 = fmaxf(a3, 0.f);
  }
  if (OUTBF16) {
    uint2 o;
    o.x = ((unsigned)f2bf(a1) << 16) | f2bf(a0);
    o.y = ((unsigned)f2bf(a3) << 16) | f2bf(a2);
    *(uint2*)&((unsigned short*)outv)[(size_t)node * HD + c0] = o;
  } else {
    *(float4*)&((float*)outv)[(size_t)node * HD + c0] = make_float4(a0, a1, a2, a3);
  }
}

// ---------------- zscore ----------------

__global__ void k_colstats(const float* __restrict__ H, float* __restrict__ stats, int N) {
  __shared__ float ss[256], sq[256];
  int t = threadIdx.x;
  int col = t & 63, grp = t >> 6;
  float s = 0.f, q = 0.f;
  for (int row = blockIdx.x * 4 + grp; row < N; row += gridDim.x * 4) {
    float v = H[(size_t)row * HD + col];
    s += v;
    q += v * v;
  }
  ss[t] = s;
  sq[t] = q;
  __syncthreads();
  if (t < 64) {
    s = ss[t] + ss[t + 64] + ss[t + 128] + ss[t + 192];
    q = sq[t] + sq[t + 64] + sq[t + 128] + sq[t + 192];
    atomicAdd(&stats[t], s);
    atomicAdd(&stats[64 + t], q);
  }
}

__global__ void k_normalize(float* __restrict__ H, const float* __restrict__ stats, int N) {
  int i = blockIdx.x * blockDim.x + threadIdx.x;
  int total = N * HD;
  if (i >= total) return;
  int col = i & 63;
  float sum = stats[col], sumsq = stats[64 + col];
  float mean = sum / (float)N;
  float var = (sumsq - sum * sum / (float)N) / (float)(N - 1);
  float r = rsqrtf(var);
  H[i] = (H[i] - mean) * r;
}

// ---------------- launch ----------------

extern "C" void kernel_launch(void* const* d_in, const int* in_sizes, int n_in,
                              void* d_out, int out_size, void* d_ws, size_t ws_size,
                              hipStream_t stream) {
  const int IN_DIM = 256;
  const float* X[2] = {(const float*)d_in[0], (const float*)d_in[2]};
  const int* EI[2] = {(const int*)d_in[1], (const int*)d_in[3]};
  const float* W1 = (const float*)d_in[4];
  const float* b1 = (const float*)d_in[5];
  const float* W2 = (const float*)d_in[6];
  const float* b2 = (const float*)d_in[7];
  const int N = in_sizes[0] / IN_DIM;
  const int E = in_sizes[1] / 2;
  const int NB = (N + (1 << BKT_SHIFT) - 1) >> BKT_SHIFT;  // buckets (98)
  const int NBLK = (E + CH - 1) / CH;                      // bin1 blocks (196)

  char* ws = (char*)d_ws;
  size_t off = 0;
  auto carve = [&](size_t bytes) -> char* {
    char* p = ws + off;
    off += (bytes + 255) & ~(size_t)255;
    return p;
  };
  unsigned short* Hb = (unsigned short*)carve((size_t)N * HD * 2);      // gemm out (bf16)
  unsigned short* bufAgg = (unsigned short*)carve((size_t)N * HD * 2);  // agg1 out (bf16)
  int* tmp = (int*)carve((size_t)NBLK * CH * 4);
  int* recs = (int*)carve((size_t)E * 4);
  char* zero_base = carve(128 * 4);  // stats[128]
  float* stats = (float*)zero_base;
  int* row_start = (int*)carve((size_t)(N + 1) * 4);
  float* dinv = (float*)carve((size_t)N * 4);
  int* bucket_base = (int*)carve((size_t)(NB + 1) * 4);
  int* counts = (int*)carve((size_t)NB * NBLK * 4);
  int* offsets = (int*)carve((size_t)NB * NBLK * 4);
  (void)ws_size; (void)n_in; (void)out_size;

  const int T = 256;
  const int gAgg = ((size_t)N * 16 + T - 1) / T;  // 16 threads per node
  const int gGemm = (N + 127) / 128;              // 128 rows per block
  const int gElem = (N * HD + T - 1) / T;

  for (int g = 0; g < 2; ++g) {
    const float* x = X[g];
    const int* src = EI[g];
    const int* dst = EI[g] + E;
    float* OUT = (float*)d_out + (size_t)g * N * HD;

    hipMemsetAsync(zero_base, 0, 128 * 4, stream);
    k_bin1<<<NBLK, T, 0, stream>>>(src, dst, tmp, counts, offsets, NB, NBLK, E);
    k_bscan<<<1, 128, 0, stream>>>(counts, bucket_base, row_start, NB, NBLK, N, E);
    k_bin2m<<<NB, 1024, 0, stream>>>(tmp, counts, offsets, bucket_base, row_start, dinv,
                                     recs, N, NBLK);

    // layer 1: h = relu(agg(x @ W1) + b1)  [agg out bf16]
    k_gemm<256, 0><<<gGemm, 512, 0, stream>>>(x, W1, Hb, N);
    k_agg<1><<<gAgg, T, 0, stream>>>(Hb, recs, row_start, dinv, b1, bufAgg, N, 1);
    // layer 2: h = agg(h1 @ W2) + b2 -> f32 straight into d_out segment
    k_gemm<64, 1><<<gGemm, 512, 0, stream>>>(bufAgg, W2, Hb, N);
    k_agg<0><<<gAgg, T, 0, stream>>>(Hb, recs, row_start, dinv, b2, OUT, N, 0);

    // zscore in place on OUT
    k_colstats<<<512, T, 0, stream>>>(OUT, stats, N);
    k_normalize<<<gElem, T, 0, stream>>>(OUT, stats, N);
  }
}

// Round 11
// 469.594 us; speedup vs baseline: 1.7274x; 1.0159x over previous
//
#include <hip/hip_runtime.h>
#include <hip/hip_bf16.h>

#define HD 64        // hidden == out dim
#define CH 8192      // edges per bin1 block
#define BKT_SHIFT 10 // 1024 nodes per bucket
#define SRC_BITS 17  // N=100000 < 2^17 -> {dstlocal:10 | src:17} fits in 27 bits
#define MAXBLK 256   // >= NBLK = ceil(E/CH) = 196

typedef __attribute__((ext_vector_type(8))) short bf16x8;
typedef __attribute__((ext_vector_type(4))) float f32x4;

__device__ inline unsigned short f2bf(float x) {
  unsigned u = __float_as_uint(x);
  unsigned r = u + 0x7FFF + ((u >> 16) & 1);
  return (unsigned short)(r >> 16);
}
__device__ inline float bf2f(unsigned short h) {
  return __uint_as_float(((unsigned)h) << 16);
}

// ---------------- binning pass 1: block-local bucket sort (no global atomics) --
__global__ __launch_bounds__(256) void k_bin1(const int* __restrict__ src,
                                              const int* __restrict__ dst,
                                              int* __restrict__ tmp,
                                              int* __restrict__ counts,
                                              int* __restrict__ offsets,
                                              int NB, int NBLK, int E) {
  __shared__ int hist[128];
  __shared__ int pref[128];
  __shared__ int lofs[128];
  __shared__ int stage[CH];  // 32 KB
  const int blk = blockIdx.x;
  const int e0 = blk * CH;
  const int len = min(CH, E - e0);
  const int t = threadIdx.x;

  for (int i = t; i < 128; i += 256) hist[i] = 0;
  __syncthreads();
  int dreg[CH / 256];
#pragma unroll
  for (int it = 0; it < CH / 256; ++it) {
    int i = t + it * 256;
    if (i < len) {
      int d = dst[e0 + i];
      dreg[it] = d;
      atomicAdd(&hist[d >> BKT_SHIFT], 1);
    }
  }
  __syncthreads();
  if (t < 128) pref[t] = hist[t];
  __syncthreads();
  for (int off = 1; off < 128; off <<= 1) {
    int v = 0;
    if (t < 128 && t >= off) v = pref[t - off];
    __syncthreads();
    if (t < 128) pref[t] += v;
    __syncthreads();
  }
  if (t < NB) {
    int ex = pref[t] - hist[t];
    lofs[t] = ex;
    counts[t * NBLK + blk] = hist[t];   // [bucket][block]
    offsets[t * NBLK + blk] = ex;
  }
  __syncthreads();
#pragma unroll
  for (int it = 0; it < CH / 256; ++it) {
    int i = t + it * 256;
    if (i < len) {
      int d = dreg[it], s = src[e0 + i];
      int slot = atomicAdd(&lofs[d >> BKT_SHIFT], 1);
      stage[slot] = ((d & ((1 << BKT_SHIFT) - 1)) << SRC_BITS) | s;
    }
  }
  __syncthreads();
  int nv = len >> 2;
  for (int i = t; i < nv; i += 256) ((int4*)(tmp + e0))[i] = ((const int4*)stage)[i];
  for (int i = (nv << 2) + t; i < len; i += 256) tmp[e0 + i] = stage[i];
}

// ---------------- bucket totals + exclusive scan (one small block) ----------
__global__ __launch_bounds__(128) void k_bscan(const int* __restrict__ counts,
                                               int* __restrict__ bucket_base,
                                               int* __restrict__ row_start,
                                               int NB, int NBLK, int N, int E) {
  __shared__ int sh[128];
  int t = threadIdx.x;
  int v = 0;
  if (t < NB) {
    const int* p = counts + t * NBLK;
    for (int i = 0; i < NBLK; ++i) v += p[i];
  }
  sh[t] = v;
  __syncthreads();
  for (int off = 1; off < 128; off <<= 1) {
    int x = (t >= off) ? sh[t - off] : 0;
    __syncthreads();
    sh[t] += x;
    __syncthreads();
  }
  if (t < NB) bucket_base[t] = sh[t] - v;  // exclusive
  if (t == 0) {
    bucket_base[NB] = E;
    row_start[N] = E;
  }
}

// ---------------- merged bin2: histogram + scan + dinv/row_start + place ----
// one block (1024 thr, 16 waves) per bucket of 1024 nodes
__global__ __launch_bounds__(1024) void k_bin2m(const int* __restrict__ tmp,
                                                const int* __restrict__ counts,
                                                const int* __restrict__ offsets,
                                                const int* __restrict__ bucket_base,
                                                int* __restrict__ row_start,
                                                float* __restrict__ dinv,
                                                int* __restrict__ recs, int N, int NBLK) {
  __shared__ int h[1 << BKT_SHIFT];     // histogram -> scan -> (excl via reg)
  __shared__ int lcur[1 << BKT_SHIFT];  // place cursors
  __shared__ int scnt[MAXBLK], soff[MAXBLK];
  const int b = blockIdx.x;
  const int t = threadIdx.x;
  const int node0 = b << BKT_SHIFT;
  const int lane = t & 63, w = t >> 6;

  h[t] = 0;
  for (int i = t; i < NBLK; i += 1024) {
    scnt[i] = counts[b * NBLK + i];
    soff[i] = offsets[b * NBLK + i];
  }
  __syncthreads();
  // pass 1: histogram by local node
  for (int blk = w; blk < NBLK; blk += 16) {
    int cnt = scnt[blk];
    const int* p = tmp + blk * CH + soff[blk];
    for (int j = lane; j < cnt; j += 64) atomicAdd(&h[p[j] >> SRC_BITS], 1);
  }
  __syncthreads();
  int deg = h[t];  // my node's degree
  __syncthreads();
  // inclusive scan over 1024 bins (in-place Hillis-Steele)
  for (int off = 1; off < 1024; off <<= 1) {
    int x = (t >= off) ? h[t - off] : 0;
    __syncthreads();
    h[t] += x;
    __syncthreads();
  }
  int base = bucket_base[b] + h[t] - deg;  // global exclusive prefix for my node
  lcur[t] = base;
  int n = node0 + t;
  if (n < N) {
    row_start[n] = base;
    dinv[n] = rsqrtf((float)deg + 1.0f);
  }
  __syncthreads();
  // pass 2: place records (writes confined to this bucket's recs window)
  for (int blk = w; blk < NBLK; blk += 16) {
    int cnt = scnt[blk];
    const int* p = tmp + blk * CH + soff[blk];
    for (int j = lane; j < cnt; j += 64) {
      int rec = p[j];
      int d = rec >> SRC_BITS;
      int s = rec & ((1 << SRC_BITS) - 1);
      int slot = atomicAdd(&lcur[d], 1);
      recs[slot] = s;
    }
  }
}

// ---------------- GEMM via MFMA, A direct from global ----------------
// 512 threads = 8 waves, 128 rows/block; B (hi, optionally lo) pre-swizzled in
// LDS. fp32 A converted in-reg via v_cvt_pk_bf16_f32 (RNE), no lo term.
template <int K, int A_BF16, int B_LO>
__global__ __launch_bounds__(512, 6) void k_gemm(const void* __restrict__ Xv,
                                                 const float* __restrict__ W,
                                                 unsigned short* __restrict__ Hb, int N) {
  constexpr int NKS = K / 32;
  __shared__ unsigned short sBhi[NKS * 4 * 64 * 8];
  __shared__ unsigned short sBlo[B_LO ? NKS * 4 * 64 * 8 : 8];
  const int tid = threadIdx.x;

  for (int idx = tid; idx < K * 64; idx += 512) {
    int k = idx >> 6, c = idx & 63;
    float wval = W[idx];
    int ks = k >> 5, r = k & 31, h2 = r >> 3, j = r & 7;
    int f = c >> 4, r16c = c & 15;
    int pos = (((ks * 4 + f) * 64) + h2 * 16 + r16c) * 8 + j;
    unsigned short hi = f2bf(wval);
    sBhi[pos] = hi;
    if (B_LO) sBlo[pos] = f2bf(wval - bf2f(hi));
  }
  __syncthreads();

  const int lane = tid & 63;
  const int wv = tid >> 6;  // 0..7
  const int r16 = lane & 15;
  const int half = lane >> 4;
  const int row = blockIdx.x * 128 + wv * 16 + r16;

  f32x4 acc[4];
#pragma unroll
  for (int f = 0; f < 4; ++f) acc[f] = (f32x4){0.f, 0.f, 0.f, 0.f};

#pragma unroll
  for (int ks = 0; ks < NKS; ++ks) {
    bf16x8 ahi;
    if constexpr (A_BF16) {
      union { uint4 u; bf16x8 v; } au;
      au.u = make_uint4(0, 0, 0, 0);
      if (row < N)
        au.u = *(const uint4*)((const unsigned short*)Xv + (size_t)row * K + ks * 32 + half * 8);
      ahi = au.v;
    } else {
      float4 v0 = make_float4(0.f, 0.f, 0.f, 0.f), v1 = v0;
      if (row < N) {
        const float* xp = (const float*)Xv + (size_t)row * K + ks * 32 + half * 8;
        v0 = *(const float4*)xp;
        v1 = *(const float4*)(xp + 4);
      }
      union { __hip_bfloat162 h[4]; bf16x8 v; } cu;
      cu.h[0] = __float22bfloat162_rn(make_float2(v0.x, v0.y));
      cu.h[1] = __float22bfloat162_rn(make_float2(v0.z, v0.w));
      cu.h[2] = __float22bfloat162_rn(make_float2(v1.x, v1.y));
      cu.h[3] = __float22bfloat162_rn(make_float2(v1.z, v1.w));
      ahi = cu.v;
    }
#pragma unroll
    for (int f = 0; f < 4; ++f) {
      bf16x8 bh = *(const bf16x8*)&sBhi[(((ks * 4 + f) * 64) + lane) * 8];
      acc[f] = __builtin_amdgcn_mfma_f32_16x16x32_bf16(ahi, bh, acc[f], 0, 0, 0);
      if constexpr (B_LO) {
        bf16x8 bl = *(const bf16x8*)&sBlo[(((ks * 4 + f) * 64) + lane) * 8];
        acc[f] = __builtin_amdgcn_mfma_f32_16x16x32_bf16(ahi, bl, acc[f], 0, 0, 0);
      }
    }
  }

  const int orow0 = blockIdx.x * 128 + wv * 16 + half * 4;
#pragma unroll
  for (int f = 0; f < 4; ++f) {
#pragma unroll
    for (int rg = 0; rg < 4; ++rg) {
      int orow = orow0 + rg;
      if (orow < N) Hb[(size_t)orow * HD + f * 16 + r16] = f2bf(acc[f][rg]);
    }
  }
}

// ---------------- Aggregation: 4 nodes/wave, 16 lanes/node, uint2 gathers ----
// 8-deep unroll -> 32 outstanding gathers per wave.
template <int OUTBF16>
__global__ __launch_bounds__(256) void k_agg(const unsigned short* __restrict__ Hb,
                                             const int* __restrict__ recs,
                                             const int* __restrict__ row_start,
                                             const float* __restrict__ dinv,
                                             const float* __restrict__ bias,
                                             void* __restrict__ outv, int N, int relu) {
  const int t = threadIdx.x;
  const int node = (blockIdx.x * blockDim.x + t) >> 4;
  const int lane16 = t & 15;
  if (node >= N) return;
  const int c0 = lane16 * 4;
  float di = dinv[node];
  float a0, a1, a2, a3;
  {
    uint2 h = *(const uint2*)&Hb[(size_t)node * HD + c0];
    float dd = di * di;
    a0 = bf2f((unsigned short)(h.x & 0xffff)) * dd;
    a1 = bf2f((unsigned short)(h.x >> 16)) * dd;
    a2 = bf2f((unsigned short)(h.y & 0xffff)) * dd;
    a3 = bf2f((unsigned short)(h.y >> 16)) * dd;
  }
  const int beg = row_start[node], end = row_start[node + 1];
  int e = beg;
  for (; e + 8 <= end; e += 8) {
    int s[8];
    uint2 g[8];
    float n[8];
#pragma unroll
    for (int j = 0; j < 8; ++j) s[j] = recs[e + j];
#pragma unroll
    for (int j = 0; j < 8; ++j) {
      g[j] = *(const uint2*)&Hb[(size_t)s[j] * HD + c0];
      n[j] = dinv[s[j]];
    }
#pragma unroll
    for (int j = 0; j < 8; ++j) {
      float nn = n[j] * di;
      a0 = fmaf(bf2f((unsigned short)(g[j].x & 0xffff)), nn, a0);
      a1 = fmaf(bf2f((unsigned short)(g[j].x >> 16)), nn, a1);
      a2 = fmaf(bf2f((unsigned short)(g[j].y & 0xffff)), nn, a2);
      a3 = fmaf(bf2f((unsigned short)(g[j].y >> 16)), nn, a3);
    }
  }
  for (; e < end; ++e) {
    int s = recs[e];
    uint2 g = *(const uint2*)&Hb[(size_t)s * HD + c0];
    float nn = dinv[s] * di;
    a0 = fmaf(bf2f((unsigned short)(g.x & 0xffff)), nn, a0);
    a1 = fmaf(bf2f((unsigned short)(g.x >> 16)), nn, a1);
    a2 = fmaf(bf2f((unsigned short)(g.y & 0xffff)), nn, a2);
    a3 = fmaf(bf2f((unsigned short)(g.y >> 16)), nn, a3);
  }
  float4 bv = *(const float4*)&bias[c0];
  a0 += bv.x; a1 += bv.y; a2 += bv.z; a3 += bv.w;
  if (relu) {
    a0 = fmaxf(a0, 0.f); a1 = fmaxf(a1, 0.f);
    a2 = fmaxf(a2, 0.f); a3 = fmaxf(a3, 0.f);
  }
  if (OUTBF16) {
    uint2 o;
    o.x = ((unsigned)f2bf(a1) << 16) | f2bf(a0);
    o.y = ((unsigned)f2bf(a3) << 16) | f2bf(a2);
    *(uint2*)&((unsigned short*)outv)[(size_t)node * HD + c0] = o;
  } else {
    *(float4*)&((float*)outv)[(size_t)node * HD + c0] = make_float4(a0, a1, a2, a3);
  }
}

// ---------------- zscore ----------------

__global__ void k_colstats(const float* __restrict__ H, float* __restrict__ stats, int N) {
  __shared__ float ss[256], sq[256];
  int t = threadIdx.x;
  int col = t & 63, grp = t >> 6;
  float s = 0.f, q = 0.f;
  for (int row = blockIdx.x * 4 + grp; row < N; row += gridDim.x * 4) {
    float v = H[(size_t)row * HD + col];
    s += v;
    q += v * v;
  }
  ss[t] = s;
  sq[t] = q;
  __syncthreads();
  if (t < 64) {
    s = ss[t] + ss[t + 64] + ss[t + 128] + ss[t + 192];
    q = sq[t] + sq[t + 64] + sq[t + 128] + sq[t + 192];
    atomicAdd(&stats[t], s);
    atomicAdd(&stats[64 + t], q);
  }
}

__global__ void k_normalize(float* __restrict__ H, const float* __restrict__ stats, int N) {
  int i = blockIdx.x * blockDim.x + threadIdx.x;
  int total = N * HD;
  if (i >= total) return;
  int col = i & 63;
  float sum = stats[col], sumsq = stats[64 + col];
  float mean = sum / (float)N;
  float var = (sumsq - sum * sum / (float)N) / (float)(N - 1);
  float r = rsqrtf(var);
  H[i] = (H[i] - mean) * r;
}

// ---------------- launch ----------------

extern "C" void kernel_launch(void* const* d_in, const int* in_sizes, int n_in,
                              void* d_out, int out_size, void* d_ws, size_t ws_size,
                              hipStream_t stream) {
  const int IN_DIM = 256;
  const float* X[2] = {(const float*)d_in[0], (const float*)d_in[2]};
  const int* EI[2] = {(const int*)d_in[1], (const int*)d_in[3]};
  const float* W1 = (const float*)d_in[4];
  const float* b1 = (const float*)d_in[5];
  const float* W2 = (const float*)d_in[6];
  const float* b2 = (const float*)d_in[7];
  const int N = in_sizes[0] / IN_DIM;
  const int E = in_sizes[1] / 2;
  const int NB = (N + (1 << BKT_SHIFT) - 1) >> BKT_SHIFT;  // buckets (98)
  const int NBLK = (E + CH - 1) / CH;                      // bin1 blocks (196)

  char* ws = (char*)d_ws;
  size_t off = 0;
  auto carve = [&](size_t bytes) -> char* {
    char* p = ws + off;
    off += (bytes + 255) & ~(size_t)255;
    return p;
  };
  unsigned short* Hb = (unsigned short*)carve((size_t)N * HD * 2);      // gemm out (bf16)
  unsigned short* bufAgg = (unsigned short*)carve((size_t)N * HD * 2);  // agg1 out (bf16)
  int* tmp = (int*)carve((size_t)NBLK * CH * 4);
  int* recs = (int*)carve((size_t)E * 4);
  char* zero_base = carve(128 * 4);  // stats[128]
  float* stats = (float*)zero_base;
  int* row_start = (int*)carve((size_t)(N + 1) * 4);
  float* dinv = (float*)carve((size_t)N * 4);
  int* bucket_base = (int*)carve((size_t)(NB + 1) * 4);
  int* counts = (int*)carve((size_t)NB * NBLK * 4);
  int* offsets = (int*)carve((size_t)NB * NBLK * 4);
  (void)ws_size; (void)n_in; (void)out_size;

  const int T = 256;
  const int gAgg = ((size_t)N * 16 + T - 1) / T;  // 16 threads per node
  const int gGemm = (N + 127) / 128;              // 128 rows per block
  const int gElem = (N * HD + T - 1) / T;

  for (int g = 0; g < 2; ++g) {
    const float* x = X[g];
    const int* src = EI[g];
    const int* dst = EI[g] + E;
    float* OUT = (float*)d_out + (size_t)g * N * HD;

    hipMemsetAsync(zero_base, 0, 128 * 4, stream);
    k_bin1<<<NBLK, T, 0, stream>>>(src, dst, tmp, counts, offsets, NB, NBLK, E);
    k_bscan<<<1, 128, 0, stream>>>(counts, bucket_base, row_start, NB, NBLK, N, E);
    k_bin2m<<<NB, 1024, 0, stream>>>(tmp, counts, offsets, bucket_base, row_start, dinv,
                                     recs, N, NBLK);

    // layer 1: h = relu(agg(x @ W1) + b1)  [agg out bf16]
    k_gemm<256, 0, 0><<<gGemm, 512, 0, stream>>>(x, W1, Hb, N);
    k_agg<1><<<gAgg, T, 0, stream>>>(Hb, recs, row_start, dinv, b1, bufAgg, N, 1);
    // layer 2: h = agg(h1 @ W2) + b2 -> f32 straight into d_out segment
    k_gemm<64, 1, 1><<<gGemm, 512, 0, stream>>>(bufAgg, W2, Hb, N);
    k_agg<0><<<gAgg, T, 0, stream>>>(Hb, recs, row_start, dinv, b2, OUT, N, 0);

    // zscore in place on OUT
    k_colstats<<<512, T, 0, stream>>>(OUT, stats, N);
    k_normalize<<<gElem, T, 0, stream>>>(OUT, stats, N);
  }
}

// Round 13
// 364.441 us; speedup vs baseline: 2.2258x; 1.2885x over previous
//
#include <hip/hip_runtime.h>
#include <hip/hip_bf16.h>

#define HD 64        // hidden == out dim
#define CH 8192      // edges per bin1 block
#define BKT_SHIFT 10 // 1024 nodes per bucket
#define SRC_BITS 17  // N=100000 < 2^17 -> {dstlocal:10 | src:17} fits in 27 bits
#define MAXBLK 256   // >= NBLK = ceil(E/CH) = 196

typedef __attribute__((ext_vector_type(8))) short bf16x8;
typedef __attribute__((ext_vector_type(4))) float f32x4;

__device__ inline unsigned short f2bf(float x) {
  unsigned u = __float_as_uint(x);
  unsigned r = u + 0x7FFF + ((u >> 16) & 1);
  return (unsigned short)(r >> 16);
}
__device__ inline float bf2f(unsigned short h) {
  return __uint_as_float(((unsigned)h) << 16);
}

// ---------------- binning pass 1 (both graphs): block-local bucket sort ------
__global__ __launch_bounds__(256) void k_bin1(const int* __restrict__ src0,
                                              const int* __restrict__ dst0,
                                              const int* __restrict__ src1,
                                              const int* __restrict__ dst1,
                                              int* __restrict__ tmp,
                                              int* __restrict__ counts,
                                              int* __restrict__ offsets,
                                              int NB, int NBLK, int E) {
  __shared__ int hist[128];
  __shared__ int pref[128];
  __shared__ int lofs[128];
  __shared__ int stage[CH];  // 32 KB
  const int g = blockIdx.x / NBLK;
  const int blk = blockIdx.x % NBLK;
  const int* __restrict__ src = g ? src1 : src0;
  const int* __restrict__ dst = g ? dst1 : dst0;
  int* __restrict__ tmpg = tmp + (size_t)g * NBLK * CH;
  int* __restrict__ cntg = counts + (size_t)g * NB * NBLK;
  int* __restrict__ offg = offsets + (size_t)g * NB * NBLK;
  const int e0 = blk * CH;
  const int len = min(CH, E - e0);
  const int t = threadIdx.x;

  for (int i = t; i < 128; i += 256) hist[i] = 0;
  __syncthreads();
  int dreg[CH / 256];
#pragma unroll
  for (int it = 0; it < CH / 256; ++it) {
    int i = t + it * 256;
    if (i < len) {
      int d = dst[e0 + i];
      dreg[it] = d;
      atomicAdd(&hist[d >> BKT_SHIFT], 1);
    }
  }
  __syncthreads();
  if (t < 128) pref[t] = hist[t];
  __syncthreads();
  for (int off = 1; off < 128; off <<= 1) {
    int v = 0;
    if (t < 128 && t >= off) v = pref[t - off];
    __syncthreads();
    if (t < 128) pref[t] += v;
    __syncthreads();
  }
  if (t < NB) {
    int ex = pref[t] - hist[t];
    lofs[t] = ex;
    cntg[t * NBLK + blk] = hist[t];   // [bucket][block]
    offg[t * NBLK + blk] = ex;
  }
  __syncthreads();
#pragma unroll
  for (int it = 0; it < CH / 256; ++it) {
    int i = t + it * 256;
    if (i < len) {
      int d = dreg[it], s = src[e0 + i];
      int slot = atomicAdd(&lofs[d >> BKT_SHIFT], 1);
      stage[slot] = ((d & ((1 << BKT_SHIFT) - 1)) << SRC_BITS) | s;
    }
  }
  __syncthreads();
  int nv = len >> 2;
  for (int i = t; i < nv; i += 256) ((int4*)(tmpg + e0))[i] = ((const int4*)stage)[i];
  for (int i = (nv << 2) + t; i < len; i += 256) tmpg[e0 + i] = stage[i];
}

// ---------------- bucket totals + exclusive scan (one block per graph) -------
__global__ __launch_bounds__(128) void k_bscan(const int* __restrict__ counts,
                                               int* __restrict__ bucket_base,
                                               int* __restrict__ row_start,
                                               int NB, int NBLK, int N, int E) {
  __shared__ int sh[128];
  const int g = blockIdx.x;
  const int* __restrict__ cntg = counts + (size_t)g * NB * NBLK;
  int* __restrict__ bbg = bucket_base + g * (NB + 1);
  int* __restrict__ rsg = row_start + (size_t)g * (N + 1);
  int t = threadIdx.x;
  int v = 0;
  if (t < NB) {
    const int* p = cntg + t * NBLK;
    for (int i = 0; i < NBLK; ++i) v += p[i];
  }
  sh[t] = v;
  __syncthreads();
  for (int off = 1; off < 128; off <<= 1) {
    int x = (t >= off) ? sh[t - off] : 0;
    __syncthreads();
    sh[t] += x;
    __syncthreads();
  }
  if (t < NB) bbg[t] = sh[t] - v;  // exclusive
  if (t == 0) {
    bbg[NB] = E;
    rsg[N] = E;
  }
}

// ---------------- merged bin2 (both graphs): hist + scan + place -------------
__global__ __launch_bounds__(1024) void k_bin2m(const int* __restrict__ tmp,
                                                const int* __restrict__ counts,
                                                const int* __restrict__ offsets,
                                                const int* __restrict__ bucket_base,
                                                int* __restrict__ row_start,
                                                float* __restrict__ dinv,
                                                int* __restrict__ recs, int N, int NB,
                                                int NBLK, int E) {
  __shared__ int h[1 << BKT_SHIFT];
  __shared__ int lcur[1 << BKT_SHIFT];
  __shared__ int scnt[MAXBLK], soff[MAXBLK];
  const int g = blockIdx.x / NB;
  const int b = blockIdx.x % NB;
  const int* __restrict__ tmpg = tmp + (size_t)g * NBLK * CH;
  const int* __restrict__ cntg = counts + (size_t)g * NB * NBLK;
  const int* __restrict__ offg = offsets + (size_t)g * NB * NBLK;
  const int* __restrict__ bbg = bucket_base + g * (NB + 1);
  int* __restrict__ rsg = row_start + (size_t)g * (N + 1);
  float* __restrict__ dig = dinv + (size_t)g * N;
  int* __restrict__ recg = recs + (size_t)g * E;
  const int t = threadIdx.x;
  const int node0 = b << BKT_SHIFT;
  const int lane = t & 63, w = t >> 6;

  h[t] = 0;
  for (int i = t; i < NBLK; i += 1024) {
    scnt[i] = cntg[b * NBLK + i];
    soff[i] = offg[b * NBLK + i];
  }
  __syncthreads();
  for (int blk = w; blk < NBLK; blk += 16) {
    int cnt = scnt[blk];
    const int* p = tmpg + blk * CH + soff[blk];
    for (int j = lane; j < cnt; j += 64) atomicAdd(&h[p[j] >> SRC_BITS], 1);
  }
  __syncthreads();
  int deg = h[t];
  __syncthreads();
  for (int off = 1; off < 1024; off <<= 1) {
    int x = (t >= off) ? h[t - off] : 0;
    __syncthreads();
    h[t] += x;
    __syncthreads();
  }
  int base = bbg[b] + h[t] - deg;
  lcur[t] = base;
  int n = node0 + t;
  if (n < N) {
    rsg[n] = base;
    dig[n] = rsqrtf((float)deg + 1.0f);
  }
  __syncthreads();
  for (int blk = w; blk < NBLK; blk += 16) {
    int cnt = scnt[blk];
    const int* p = tmpg + blk * CH + soff[blk];
    for (int j = lane; j < cnt; j += 64) {
      int rec = p[j];
      int d = rec >> SRC_BITS;
      int s = rec & ((1 << SRC_BITS) - 1);
      int slot = atomicAdd(&lcur[d], 1);
      recg[slot] = s;
    }
  }
}

// ---------------- GEMM via MFMA (both graphs), A direct from global ----------
// 512 threads = 8 waves, 128 rows/block; B pre-swizzled in LDS.
template <int K, int A_BF16, int B_LO>
__global__ __launch_bounds__(512, 6) void k_gemm(const void* __restrict__ Xv0,
                                                 const void* __restrict__ Xv1,
                                                 const float* __restrict__ W,
                                                 unsigned short* __restrict__ Hb, int N,
                                                 int gPer) {
  constexpr int NKS = K / 32;
  __shared__ unsigned short sBhi[NKS * 4 * 64 * 8];
  __shared__ unsigned short sBlo[B_LO ? NKS * 4 * 64 * 8 : 8];
  const int tid = threadIdx.x;
  const int g = blockIdx.x / gPer;
  const int bblk = blockIdx.x % gPer;
  const void* __restrict__ Xv = g ? Xv1 : Xv0;

  for (int idx = tid; idx < K * 64; idx += 512) {
    int k = idx >> 6, c = idx & 63;
    float wval = W[idx];
    int ks = k >> 5, r = k & 31, h2 = r >> 3, j = r & 7;
    int f = c >> 4, r16c = c & 15;
    int pos = (((ks * 4 + f) * 64) + h2 * 16 + r16c) * 8 + j;
    unsigned short hi = f2bf(wval);
    sBhi[pos] = hi;
    if (B_LO) sBlo[pos] = f2bf(wval - bf2f(hi));
  }
  __syncthreads();

  const int lane = tid & 63;
  const int wv = tid >> 6;
  const int r16 = lane & 15;
  const int half = lane >> 4;
  const int row = bblk * 128 + wv * 16 + r16;

  f32x4 acc[4];
#pragma unroll
  for (int f = 0; f < 4; ++f) acc[f] = (f32x4){0.f, 0.f, 0.f, 0.f};

#pragma unroll
  for (int ks = 0; ks < NKS; ++ks) {
    bf16x8 ahi;
    if constexpr (A_BF16) {
      union { uint4 u; bf16x8 v; } au;
      au.u = make_uint4(0, 0, 0, 0);
      if (row < N)
        au.u = *(const uint4*)((const unsigned short*)Xv + (size_t)row * K + ks * 32 + half * 8);
      ahi = au.v;
    } else {
      float4 v0 = make_float4(0.f, 0.f, 0.f, 0.f), v1 = v0;
      if (row < N) {
        const float* xp = (const float*)Xv + (size_t)row * K + ks * 32 + half * 8;
        v0 = *(const float4*)xp;
        v1 = *(const float4*)(xp + 4);
      }
      union { __hip_bfloat162 h[4]; bf16x8 v; } cu;
      cu.h[0] = __float22bfloat162_rn(make_float2(v0.x, v0.y));
      cu.h[1] = __float22bfloat162_rn(make_float2(v0.z, v0.w));
      cu.h[2] = __float22bfloat162_rn(make_float2(v1.x, v1.y));
      cu.h[3] = __float22bfloat162_rn(make_float2(v1.z, v1.w));
      ahi = cu.v;
    }
#pragma unroll
    for (int f = 0; f < 4; ++f) {
      bf16x8 bh = *(const bf16x8*)&sBhi[(((ks * 4 + f) * 64) + lane) * 8];
      acc[f] = __builtin_amdgcn_mfma_f32_16x16x32_bf16(ahi, bh, acc[f], 0, 0, 0);
      if constexpr (B_LO) {
        bf16x8 bl = *(const bf16x8*)&sBlo[(((ks * 4 + f) * 64) + lane) * 8];
        acc[f] = __builtin_amdgcn_mfma_f32_16x16x32_bf16(ahi, bl, acc[f], 0, 0, 0);
      }
    }
  }

  const int orow0 = bblk * 128 + wv * 16 + half * 4;
#pragma unroll
  for (int f = 0; f < 4; ++f) {
#pragma unroll
    for (int rg = 0; rg < 4; ++rg) {
      int orow = orow0 + rg;
      if (orow < N) Hb[((size_t)g * N + orow) * HD + f * 16 + r16] = f2bf(acc[f][rg]);
    }
  }
}

// ---------------- Aggregation (both graphs): 16 lanes/node, uint2 gathers ----
template <int OUTBF16>
__global__ __launch_bounds__(256) void k_agg(const unsigned short* __restrict__ Hb,
                                             const int* __restrict__ recs,
                                             const int* __restrict__ row_start,
                                             const float* __restrict__ dinv,
                                             const float* __restrict__ bias,
                                             void* __restrict__ outv, int N, int E,
                                             int relu) {
  const int t = threadIdx.x;
  const int nglob = (blockIdx.x * blockDim.x + t) >> 4;
  const int lane16 = t & 15;
  if (nglob >= 2 * N) return;
  const int g = nglob >= N;
  const int node = nglob - g * N;
  const int* __restrict__ rsg = row_start + (size_t)g * (N + 1);
  const int* __restrict__ R = recs + (size_t)g * E;
  const float* __restrict__ dig = dinv + (size_t)g * N;
  const unsigned short* __restrict__ Hbg = Hb + (size_t)g * N * HD;

  const int c0 = lane16 * 4;
  float di = dig[node];
  float a0, a1, a2, a3;
  {
    uint2 h = *(const uint2*)&Hbg[(size_t)node * HD + c0];
    float dd = di * di;
    a0 = bf2f((unsigned short)(h.x & 0xffff)) * dd;
    a1 = bf2f((unsigned short)(h.x >> 16)) * dd;
    a2 = bf2f((unsigned short)(h.y & 0xffff)) * dd;
    a3 = bf2f((unsigned short)(h.y >> 16)) * dd;
  }
  const int beg = rsg[node], end = rsg[node + 1];
  int e = beg;
  for (; e + 8 <= end; e += 8) {
    int s[8];
    uint2 gg[8];
    float n[8];
#pragma unroll
    for (int j = 0; j < 8; ++j) s[j] = R[e + j];
#pragma unroll
    for (int j = 0; j < 8; ++j) {
      gg[j] = *(const uint2*)&Hbg[(size_t)s[j] * HD + c0];
      n[j] = dig[s[j]];
    }
#pragma unroll
    for (int j = 0; j < 8; ++j) {
      float nn = n[j] * di;
      a0 = fmaf(bf2f((unsigned short)(gg[j].x & 0xffff)), nn, a0);
      a1 = fmaf(bf2f((unsigned short)(gg[j].x >> 16)), nn, a1);
      a2 = fmaf(bf2f((unsigned short)(gg[j].y & 0xffff)), nn, a2);
      a3 = fmaf(bf2f((unsigned short)(gg[j].y >> 16)), nn, a3);
    }
  }
  for (; e < end; ++e) {
    int s = R[e];
    uint2 gg = *(const uint2*)&Hbg[(size_t)s * HD + c0];
    float nn = dig[s] * di;
    a0 = fmaf(bf2f((unsigned short)(gg.x & 0xffff)), nn, a0);
    a1 = fmaf(bf2f((unsigned short)(gg.x >> 16)), nn, a1);
    a2 = fmaf(bf2f((unsigned short)(gg.y & 0xffff)), nn, a2);
    a3 = fmaf(bf2f((unsigned short)(gg.y >> 16)), nn, a3);
  }
  float4 bv = *(const float4*)&bias[c0];
  a0 += bv.x; a1 += bv.y; a2 += bv.z; a3 += bv.w;
  if (relu) {
    a0 = fmaxf(a0, 0.f); a1 = fmaxf(a1, 0.f);
    a2 = fmaxf(a2, 0.f); a3 = fmaxf(a3, 0.f);
  }
  if (OUTBF16) {
    uint2 o;
    o.x = ((unsigned)f2bf(a1) << 16) | f2bf(a0);
    o.y = ((unsigned)f2bf(a3) << 16) | f2bf(a2);
    *(uint2*)&((unsigned short*)outv)[(size_t)nglob * HD + c0] = o;
  } else {
    *(float4*)&((float*)outv)[(size_t)nglob * HD + c0] = make_float4(a0, a1, a2, a3);
  }
}

// ---------------- zscore (both graphs) ----------------

__global__ void k_colstats(const float* __restrict__ H, float* __restrict__ stats, int N,
                           int gridPer) {
  __shared__ float ss[256], sq[256];
  const int g = blockIdx.x / gridPer;
  const int blk = blockIdx.x % gridPer;
  const float* __restrict__ Hg = H + (size_t)g * N * HD;
  float* __restrict__ st = stats + g * 128;
  int t = threadIdx.x;
  int col = t & 63, grp = t >> 6;
  float s = 0.f, q = 0.f;
  for (int row = blk * 4 + grp; row < N; row += gridPer * 4) {
    float v = Hg[(size_t)row * HD + col];
    s += v;
    q += v * v;
  }
  ss[t] = s;
  sq[t] = q;
  __syncthreads();
  if (t < 64) {
    s = ss[t] + ss[t + 64] + ss[t + 128] + ss[t + 192];
    q = sq[t] + sq[t + 64] + sq[t + 128] + sq[t + 192];
    atomicAdd(&st[t], s);
    atomicAdd(&st[64 + t], q);
  }
}

__global__ void k_normalize(float* __restrict__ H, const float* __restrict__ stats, int N) {
  int i = blockIdx.x * blockDim.x + threadIdx.x;
  int total = 2 * N * HD;
  if (i >= total) return;
  int col = i & 63;
  const float* st = stats + (i >= N * HD ? 128 : 0);
  float sum = st[col], sumsq = st[64 + col];
  float mean = sum / (float)N;
  float var = (sumsq - sum * sum / (float)N) / (float)(N - 1);
  float r = rsqrtf(var);
  H[i] = (H[i] - mean) * r;
}

// ---------------- launch ----------------

extern "C" void kernel_launch(void* const* d_in, const int* in_sizes, int n_in,
                              void* d_out, int out_size, void* d_ws, size_t ws_size,
                              hipStream_t stream) {
  const int IN_DIM = 256;
  const float* X1 = (const float*)d_in[0];
  const float* X2 = (const float*)d_in[2];
  const int* EI1 = (const int*)d_in[1];
  const int* EI2 = (const int*)d_in[3];
  const float* W1 = (const float*)d_in[4];
  const float* b1 = (const float*)d_in[5];
  const float* W2 = (const float*)d_in[6];
  const float* b2 = (const float*)d_in[7];
  const int N = in_sizes[0] / IN_DIM;
  const int E = in_sizes[1] / 2;
  const int NB = (N + (1 << BKT_SHIFT) - 1) >> BKT_SHIFT;  // 98
  const int NBLK = (E + CH - 1) / CH;                      // 196

  char* ws = (char*)d_ws;
  size_t off = 0;
  auto carve = [&](size_t bytes) -> char* {
    char* p = ws + off;
    off += (bytes + 255) & ~(size_t)255;
    return p;
  };
  unsigned short* Hb = (unsigned short*)carve((size_t)2 * N * HD * 2);  // both graphs
  int* tmp = (int*)carve((size_t)2 * NBLK * CH * 4);
  int* recs = (int*)carve((size_t)2 * E * 4);
  char* zero_base = carve(256 * 4);  // stats[2][128]
  float* stats = (float*)zero_base;
  int* row_start = (int*)carve((size_t)2 * (N + 1) * 4);
  float* dinv = (float*)carve((size_t)2 * N * 4);
  int* bucket_base = (int*)carve((size_t)2 * (NB + 1) * 4);
  int* counts = (int*)carve((size_t)2 * NB * NBLK * 4);
  int* offsets = (int*)carve((size_t)2 * NB * NBLK * 4);
  unsigned short* bufAgg = (unsigned short*)d_out;  // alias: dead before agg2 writes
  (void)ws_size; (void)n_in; (void)out_size;

  const int T = 256;
  const int gPer1 = (N + 127) / 128;
  const int gPer2 = (2 * N + 127) / 128;
  const int gAgg = (2 * N * 16 + T - 1) / T;
  const int gCS = 512;
  const int gElem = (2 * N * HD + T - 1) / T;

  (void)hipMemsetAsync(zero_base, 0, 256 * 4, stream);
  k_bin1<<<2 * NBLK, T, 0, stream>>>(EI1, EI1 + E, EI2, EI2 + E, tmp, counts, offsets,
                                     NB, NBLK, E);
  k_bscan<<<2, 128, 0, stream>>>(counts, bucket_base, row_start, NB, NBLK, N, E);
  k_bin2m<<<2 * NB, 1024, 0, stream>>>(tmp, counts, offsets, bucket_base, row_start,
                                       dinv, recs, N, NB, NBLK, E);

  // layer 1 (both graphs): h = relu(agg(x @ W1) + b1) -> bufAgg (bf16, in d_out)
  k_gemm<256, 0, 0><<<2 * gPer1, 512, 0, stream>>>(X1, X2, W1, Hb, N, gPer1);
  k_agg<1><<<gAgg, T, 0, stream>>>(Hb, recs, row_start, dinv, b1, bufAgg, N, E, 1);
  // layer 2 (both graphs as one 2N-row GEMM): h2 = agg(h1 @ W2) + b2 -> d_out f32
  k_gemm<64, 1, 1><<<gPer2, 512, 0, stream>>>(bufAgg, bufAgg, W2, Hb, 2 * N, gPer2);
  k_agg<0><<<gAgg, T, 0, stream>>>(Hb, recs, row_start, dinv, b2, d_out, N, E, 0);

  // zscore in place on d_out (per graph)
  k_colstats<<<2 * gCS, T, 0, stream>>>((float*)d_out, stats, N, gCS);
  k_normalize<<<gElem, T, 0, stream>>>((float*)d_out, stats, N);
}

// Round 14
// 364.157 us; speedup vs baseline: 2.2276x; 1.0008x over previous
//
#include <hip/hip_runtime.h>
#include <hip/hip_bf16.h>

#define HD 64        // hidden == out dim
#define CH 8192      // edges per bin1 block
#define BKT_SHIFT 10 // 1024 nodes per bucket
#define SRC_BITS 17  // N=100000 < 2^17 -> {dstlocal:10 | src:17} fits in 27 bits
#define MAXBLK 256   // >= NBLK = ceil(E/CH) = 196

typedef __attribute__((ext_vector_type(8))) short bf16x8;
typedef __attribute__((ext_vector_type(4))) float f32x4;

__device__ inline unsigned short f2bf(float x) {
  unsigned u = __float_as_uint(x);
  unsigned r = u + 0x7FFF + ((u >> 16) & 1);
  return (unsigned short)(r >> 16);
}
__device__ inline float bf2f(unsigned short h) {
  return __uint_as_float(((unsigned)h) << 16);
}

// ---------------- binning pass 1 (both graphs): block-local bucket sort ------
__global__ __launch_bounds__(256) void k_bin1(const int* __restrict__ src0,
                                              const int* __restrict__ dst0,
                                              const int* __restrict__ src1,
                                              const int* __restrict__ dst1,
                                              int* __restrict__ tmp,
                                              int* __restrict__ counts,
                                              int* __restrict__ offsets,
                                              int NB, int NBLK, int E) {
  __shared__ int hist[128];
  __shared__ int pref[128];
  __shared__ int lofs[128];
  __shared__ int stage[CH];  // 32 KB
  const int g = blockIdx.x / NBLK;
  const int blk = blockIdx.x % NBLK;
  const int* __restrict__ src = g ? src1 : src0;
  const int* __restrict__ dst = g ? dst1 : dst0;
  int* __restrict__ tmpg = tmp + (size_t)g * NBLK * CH;
  int* __restrict__ cntg = counts + (size_t)g * NB * NBLK;
  int* __restrict__ offg = offsets + (size_t)g * NB * NBLK;
  const int e0 = blk * CH;
  const int len = min(CH, E - e0);
  const int t = threadIdx.x;

  for (int i = t; i < 128; i += 256) hist[i] = 0;
  __syncthreads();
  int dreg[CH / 256];
#pragma unroll
  for (int it = 0; it < CH / 256; ++it) {
    int i = t + it * 256;
    if (i < len) {
      int d = dst[e0 + i];
      dreg[it] = d;
      atomicAdd(&hist[d >> BKT_SHIFT], 1);
    }
  }
  __syncthreads();
  if (t < 128) pref[t] = hist[t];
  __syncthreads();
  for (int off = 1; off < 128; off <<= 1) {
    int v = 0;
    if (t < 128 && t >= off) v = pref[t - off];
    __syncthreads();
    if (t < 128) pref[t] += v;
    __syncthreads();
  }
  if (t < NB) {
    int ex = pref[t] - hist[t];
    lofs[t] = ex;
    cntg[t * NBLK + blk] = hist[t];   // [bucket][block]
    offg[t * NBLK + blk] = ex;
  }
  __syncthreads();
#pragma unroll
  for (int it = 0; it < CH / 256; ++it) {
    int i = t + it * 256;
    if (i < len) {
      int d = dreg[it], s = src[e0 + i];
      int slot = atomicAdd(&lofs[d >> BKT_SHIFT], 1);
      stage[slot] = ((d & ((1 << BKT_SHIFT) - 1)) << SRC_BITS) | s;
    }
  }
  __syncthreads();
  int nv = len >> 2;
  for (int i = t; i < nv; i += 256) ((int4*)(tmpg + e0))[i] = ((const int4*)stage)[i];
  for (int i = (nv << 2) + t; i < len; i += 256) tmpg[e0 + i] = stage[i];
}

// ---------------- bucket totals + exclusive scan (one block per graph) -------
__global__ __launch_bounds__(128) void k_bscan(const int* __restrict__ counts,
                                               int* __restrict__ bucket_base,
                                               int* __restrict__ row_start,
                                               int NB, int NBLK, int N, int E) {
  __shared__ int sh[128];
  const int g = blockIdx.x;
  const int* __restrict__ cntg = counts + (size_t)g * NB * NBLK;
  int* __restrict__ bbg = bucket_base + g * (NB + 1);
  int* __restrict__ rsg = row_start + (size_t)g * (N + 1);
  int t = threadIdx.x;
  int v = 0;
  if (t < NB) {
    const int* p = cntg + t * NBLK;
    for (int i = 0; i < NBLK; ++i) v += p[i];
  }
  sh[t] = v;
  __syncthreads();
  for (int off = 1; off < 128; off <<= 1) {
    int x = (t >= off) ? sh[t - off] : 0;
    __syncthreads();
    sh[t] += x;
    __syncthreads();
  }
  if (t < NB) bbg[t] = sh[t] - v;  // exclusive
  if (t == 0) {
    bbg[NB] = E;
    rsg[N] = E;
  }
}

// ---------------- merged bin2 (both graphs): hist + scan + place -------------
__global__ __launch_bounds__(1024) void k_bin2m(const int* __restrict__ tmp,
                                                const int* __restrict__ counts,
                                                const int* __restrict__ offsets,
                                                const int* __restrict__ bucket_base,
                                                int* __restrict__ row_start,
                                                float* __restrict__ dinv,
                                                int* __restrict__ recs, int N, int NB,
                                                int NBLK, int E) {
  __shared__ int h[1 << BKT_SHIFT];
  __shared__ int lcur[1 << BKT_SHIFT];
  __shared__ int scnt[MAXBLK], soff[MAXBLK];
  const int g = blockIdx.x / NB;
  const int b = blockIdx.x % NB;
  const int* __restrict__ tmpg = tmp + (size_t)g * NBLK * CH;
  const int* __restrict__ cntg = counts + (size_t)g * NB * NBLK;
  const int* __restrict__ offg = offsets + (size_t)g * NB * NBLK;
  const int* __restrict__ bbg = bucket_base + g * (NB + 1);
  int* __restrict__ rsg = row_start + (size_t)g * (N + 1);
  float* __restrict__ dig = dinv + (size_t)g * N;
  int* __restrict__ recg = recs + (size_t)g * E;
  const int t = threadIdx.x;
  const int node0 = b << BKT_SHIFT;
  const int lane = t & 63, w = t >> 6;

  h[t] = 0;
  for (int i = t; i < NBLK; i += 1024) {
    scnt[i] = cntg[b * NBLK + i];
    soff[i] = offg[b * NBLK + i];
  }
  __syncthreads();
  for (int blk = w; blk < NBLK; blk += 16) {
    int cnt = scnt[blk];
    const int* p = tmpg + blk * CH + soff[blk];
    for (int j = lane; j < cnt; j += 64) atomicAdd(&h[p[j] >> SRC_BITS], 1);
  }
  __syncthreads();
  int deg = h[t];
  __syncthreads();
  for (int off = 1; off < 1024; off <<= 1) {
    int x = (t >= off) ? h[t - off] : 0;
    __syncthreads();
    h[t] += x;
    __syncthreads();
  }
  int base = bbg[b] + h[t] - deg;
  lcur[t] = base;
  int n = node0 + t;
  if (n < N) {
    rsg[n] = base;
    dig[n] = rsqrtf((float)deg + 1.0f);
  }
  __syncthreads();
  for (int blk = w; blk < NBLK; blk += 16) {
    int cnt = scnt[blk];
    const int* p = tmpg + blk * CH + soff[blk];
    for (int j = lane; j < cnt; j += 64) {
      int rec = p[j];
      int d = rec >> SRC_BITS;
      int s = rec & ((1 << SRC_BITS) - 1);
      int slot = atomicAdd(&lcur[d], 1);
      recg[slot] = s;
    }
  }
}

// ---------------- GEMM via MFMA (both graphs), A direct from global ----------
// 512 threads = 8 waves, 128 rows/block; B pre-swizzled in LDS.
// All A-loads for the whole K issued up front (load pass), then cvt+MFMA pass:
// forces ~16 outstanding global loads per wave (the r13 profile showed the
// compiler serializing at VGPR=24 with ~2 in flight).
template <int K, int A_BF16, int B_LO>
__global__ __launch_bounds__(512, 4) void k_gemm(const void* __restrict__ Xv0,
                                                 const void* __restrict__ Xv1,
                                                 const float* __restrict__ W,
                                                 unsigned short* __restrict__ Hb, int N,
                                                 int gPer) {
  constexpr int NKS = K / 32;
  __shared__ unsigned short sBhi[NKS * 4 * 64 * 8];
  __shared__ unsigned short sBlo[B_LO ? NKS * 4 * 64 * 8 : 8];
  const int tid = threadIdx.x;
  const int g = blockIdx.x / gPer;
  const int bblk = blockIdx.x % gPer;
  const void* __restrict__ Xv = g ? Xv1 : Xv0;

  for (int idx = tid; idx < K * 64; idx += 512) {
    int k = idx >> 6, c = idx & 63;
    float wval = W[idx];
    int ks = k >> 5, r = k & 31, h2 = r >> 3, j = r & 7;
    int f = c >> 4, r16c = c & 15;
    int pos = (((ks * 4 + f) * 64) + h2 * 16 + r16c) * 8 + j;
    unsigned short hi = f2bf(wval);
    sBhi[pos] = hi;
    if (B_LO) sBlo[pos] = f2bf(wval - bf2f(hi));
  }
  __syncthreads();

  const int lane = tid & 63;
  const int wv = tid >> 6;
  const int r16 = lane & 15;
  const int half = lane >> 4;
  const int row = bblk * 128 + wv * 16 + r16;

  f32x4 acc[4];
#pragma unroll
  for (int f = 0; f < 4; ++f) acc[f] = (f32x4){0.f, 0.f, 0.f, 0.f};

  // ---- pass 1: issue ALL A loads ----
  uint4 abf[A_BF16 ? NKS : 1];
  float4 af0[A_BF16 ? 1 : NKS], af1[A_BF16 ? 1 : NKS];
#pragma unroll
  for (int ks = 0; ks < NKS; ++ks) {
    if constexpr (A_BF16) {
      abf[ks] = make_uint4(0, 0, 0, 0);
      if (row < N)
        abf[ks] = *(const uint4*)((const unsigned short*)Xv + (size_t)row * K + ks * 32 + half * 8);
    } else {
      af0[ks] = make_float4(0.f, 0.f, 0.f, 0.f);
      af1[ks] = af0[ks];
      if (row < N) {
        const float* xp = (const float*)Xv + (size_t)row * K + ks * 32 + half * 8;
        af0[ks] = *(const float4*)xp;
        af1[ks] = *(const float4*)(xp + 4);
      }
    }
  }

  // ---- pass 2: convert + MFMA ----
#pragma unroll
  for (int ks = 0; ks < NKS; ++ks) {
    bf16x8 ahi;
    if constexpr (A_BF16) {
      union { uint4 u; bf16x8 v; } au;
      au.u = abf[ks];
      ahi = au.v;
    } else {
      union { __hip_bfloat162 h[4]; bf16x8 v; } cu;
      cu.h[0] = __float22bfloat162_rn(make_float2(af0[ks].x, af0[ks].y));
      cu.h[1] = __float22bfloat162_rn(make_float2(af0[ks].z, af0[ks].w));
      cu.h[2] = __float22bfloat162_rn(make_float2(af1[ks].x, af1[ks].y));
      cu.h[3] = __float22bfloat162_rn(make_float2(af1[ks].z, af1[ks].w));
      ahi = cu.v;
    }
#pragma unroll
    for (int f = 0; f < 4; ++f) {
      bf16x8 bh = *(const bf16x8*)&sBhi[(((ks * 4 + f) * 64) + lane) * 8];
      acc[f] = __builtin_amdgcn_mfma_f32_16x16x32_bf16(ahi, bh, acc[f], 0, 0, 0);
      if constexpr (B_LO) {
        bf16x8 bl = *(const bf16x8*)&sBlo[(((ks * 4 + f) * 64) + lane) * 8];
        acc[f] = __builtin_amdgcn_mfma_f32_16x16x32_bf16(ahi, bl, acc[f], 0, 0, 0);
      }
    }
  }

  const int orow0 = bblk * 128 + wv * 16 + half * 4;
#pragma unroll
  for (int f = 0; f < 4; ++f) {
#pragma unroll
    for (int rg = 0; rg < 4; ++rg) {
      int orow = orow0 + rg;
      if (orow < N) Hb[((size_t)g * N + orow) * HD + f * 16 + r16] = f2bf(acc[f][rg]);
    }
  }
}

// ---------------- Aggregation (both graphs): 16 lanes/node, uint2 gathers ----
template <int OUTBF16>
__global__ __launch_bounds__(256) void k_agg(const unsigned short* __restrict__ Hb,
                                             const int* __restrict__ recs,
                                             const int* __restrict__ row_start,
                                             const float* __restrict__ dinv,
                                             const float* __restrict__ bias,
                                             void* __restrict__ outv, int N, int E,
                                             int relu) {
  const int t = threadIdx.x;
  const int nglob = (blockIdx.x * blockDim.x + t) >> 4;
  const int lane16 = t & 15;
  if (nglob >= 2 * N) return;
  const int g = nglob >= N;
  const int node = nglob - g * N;
  const int* __restrict__ rsg = row_start + (size_t)g * (N + 1);
  const int* __restrict__ R = recs + (size_t)g * E;
  const float* __restrict__ dig = dinv + (size_t)g * N;
  const unsigned short* __restrict__ Hbg = Hb + (size_t)g * N * HD;

  const int c0 = lane16 * 4;
  float di = dig[node];
  float a0, a1, a2, a3;
  {
    uint2 h = *(const uint2*)&Hbg[(size_t)node * HD + c0];
    float dd = di * di;
    a0 = bf2f((unsigned short)(h.x & 0xffff)) * dd;
    a1 = bf2f((unsigned short)(h.x >> 16)) * dd;
    a2 = bf2f((unsigned short)(h.y & 0xffff)) * dd;
    a3 = bf2f((unsigned short)(h.y >> 16)) * dd;
  }
  const int beg = rsg[node], end = rsg[node + 1];
  int e = beg;
  for (; e + 8 <= end; e += 8) {
    int s[8];
    uint2 gg[8];
    float n[8];
#pragma unroll
    for (int j = 0; j < 8; ++j) s[j] = R[e + j];
#pragma unroll
    for (int j = 0; j < 8; ++j) {
      gg[j] = *(const uint2*)&Hbg[(size_t)s[j] * HD + c0];
      n[j] = dig[s[j]];
    }
#pragma unroll
    for (int j = 0; j < 8; ++j) {
      float nn = n[j] * di;
      a0 = fmaf(bf2f((unsigned short)(gg[j].x & 0xffff)), nn, a0);
      a1 = fmaf(bf2f((unsigned short)(gg[j].x >> 16)), nn, a1);
      a2 = fmaf(bf2f((unsigned short)(gg[j].y & 0xffff)), nn, a2);
      a3 = fmaf(bf2f((unsigned short)(gg[j].y >> 16)), nn, a3);
    }
  }
  for (; e < end; ++e) {
    int s = R[e];
    uint2 gg = *(const uint2*)&Hbg[(size_t)s * HD + c0];
    float nn = dig[s] * di;
    a0 = fmaf(bf2f((unsigned short)(gg.x & 0xffff)), nn, a0);
    a1 = fmaf(bf2f((unsigned short)(gg.x >> 16)), nn, a1);
    a2 = fmaf(bf2f((unsigned short)(gg.y & 0xffff)), nn, a2);
    a3 = fmaf(bf2f((unsigned short)(gg.y >> 16)), nn, a3);
  }
  float4 bv = *(const float4*)&bias[c0];
  a0 += bv.x; a1 += bv.y; a2 += bv.z; a3 += bv.w;
  if (relu) {
    a0 = fmaxf(a0, 0.f); a1 = fmaxf(a1, 0.f);
    a2 = fmaxf(a2, 0.f); a3 = fmaxf(a3, 0.f);
  }
  if (OUTBF16) {
    uint2 o;
    o.x = ((unsigned)f2bf(a1) << 16) | f2bf(a0);
    o.y = ((unsigned)f2bf(a3) << 16) | f2bf(a2);
    *(uint2*)&((unsigned short*)outv)[(size_t)nglob * HD + c0] = o;
  } else {
    *(float4*)&((float*)outv)[(size_t)nglob * HD + c0] = make_float4(a0, a1, a2, a3);
  }
}

// ---------------- zscore (both graphs) ----------------

__global__ void k_colstats(const float* __restrict__ H, float* __restrict__ stats, int N,
                           int gridPer) {
  __shared__ float ss[256], sq[256];
  const int g = blockIdx.x / gridPer;
  const int blk = blockIdx.x % gridPer;
  const float* __restrict__ Hg = H + (size_t)g * N * HD;
  float* __restrict__ st = stats + g * 128;
  int t = threadIdx.x;
  int col = t & 63, grp = t >> 6;
  float s = 0.f, q = 0.f;
  for (int row = blk * 4 + grp; row < N; row += gridPer * 4) {
    float v = Hg[(size_t)row * HD + col];
    s += v;
    q += v * v;
  }
  ss[t] = s;
  sq[t] = q;
  __syncthreads();
  if (t < 64) {
    s = ss[t] + ss[t + 64] + ss[t + 128] + ss[t + 192];
    q = sq[t] + sq[t + 64] + sq[t + 128] + sq[t + 192];
    atomicAdd(&st[t], s);
    atomicAdd(&st[64 + t], q);
  }
}

__global__ void k_normalize(float* __restrict__ H, const float* __restrict__ stats, int N) {
  int i = blockIdx.x * blockDim.x + threadIdx.x;
  int total = 2 * N * HD;
  if (i >= total) return;
  int col = i & 63;
  const float* st = stats + (i >= N * HD ? 128 : 0);
  float sum = st[col], sumsq = st[64 + col];
  float mean = sum / (float)N;
  float var = (sumsq - sum * sum / (float)N) / (float)(N - 1);
  float r = rsqrtf(var);
  H[i] = (H[i] - mean) * r;
}

// ---------------- launch ----------------

extern "C" void kernel_launch(void* const* d_in, const int* in_sizes, int n_in,
                              void* d_out, int out_size, void* d_ws, size_t ws_size,
                              hipStream_t stream) {
  const int IN_DIM = 256;
  const float* X1 = (const float*)d_in[0];
  const float* X2 = (const float*)d_in[2];
  const int* EI1 = (const int*)d_in[1];
  const int* EI2 = (const int*)d_in[3];
  const float* W1 = (const float*)d_in[4];
  const float* b1 = (const float*)d_in[5];
  const float* W2 = (const float*)d_in[6];
  const float* b2 = (const float*)d_in[7];
  const int N = in_sizes[0] / IN_DIM;
  const int E = in_sizes[1] / 2;
  const int NB = (N + (1 << BKT_SHIFT) - 1) >> BKT_SHIFT;  // 98
  const int NBLK = (E + CH - 1) / CH;                      // 196

  char* ws = (char*)d_ws;
  size_t off = 0;
  auto carve = [&](size_t bytes) -> char* {
    char* p = ws + off;
    off += (bytes + 255) & ~(size_t)255;
    return p;
  };
  unsigned short* Hb = (unsigned short*)carve((size_t)2 * N * HD * 2);  // both graphs
  int* tmp = (int*)carve((size_t)2 * NBLK * CH * 4);
  int* recs = (int*)carve((size_t)2 * E * 4);
  char* zero_base = carve(256 * 4);  // stats[2][128]
  float* stats = (float*)zero_base;
  int* row_start = (int*)carve((size_t)2 * (N + 1) * 4);
  float* dinv = (float*)carve((size_t)2 * N * 4);
  int* bucket_base = (int*)carve((size_t)2 * (NB + 1) * 4);
  int* counts = (int*)carve((size_t)2 * NB * NBLK * 4);
  int* offsets = (int*)carve((size_t)2 * NB * NBLK * 4);
  unsigned short* bufAgg = (unsigned short*)d_out;  // alias: dead before agg2 writes
  (void)ws_size; (void)n_in; (void)out_size;

  const int T = 256;
  const int gPer1 = (N + 127) / 128;
  const int gPer2 = (2 * N + 127) / 128;
  const int gAgg = (2 * N * 16 + T - 1) / T;
  const int gCS = 512;
  const int gElem = (2 * N * HD + T - 1) / T;

  (void)hipMemsetAsync(zero_base, 0, 256 * 4, stream);
  k_bin1<<<2 * NBLK, T, 0, stream>>>(EI1, EI1 + E, EI2, EI2 + E, tmp, counts, offsets,
                                     NB, NBLK, E);
  k_bscan<<<2, 128, 0, stream>>>(counts, bucket_base, row_start, NB, NBLK, N, E);
  k_bin2m<<<2 * NB, 1024, 0, stream>>>(tmp, counts, offsets, bucket_base, row_start,
                                       dinv, recs, N, NB, NBLK, E);

  // layer 1 (both graphs): h = relu(agg(x @ W1) + b1) -> bufAgg (bf16, in d_out)
  k_gemm<256, 0, 0><<<2 * gPer1, 512, 0, stream>>>(X1, X2, W1, Hb, N, gPer1);
  k_agg<1><<<gAgg, T, 0, stream>>>(Hb, recs, row_start, dinv, b1, bufAgg, N, E, 1);
  // layer 2 (both graphs as one 2N-row GEMM): h2 = agg(h1 @ W2) + b2 -> d_out f32
  k_gemm<64, 1, 1><<<gPer2, 512, 0, stream>>>(bufAgg, bufAgg, W2, Hb, 2 * N, gPer2);
  k_agg<0><<<gAgg, T, 0, stream>>>(Hb, recs, row_start, dinv, b2, d_out, N, E, 0);

  // zscore in place on d_out (per graph)
  k_colstats<<<2 * gCS, T, 0, stream>>>((float*)d_out, stats, N, gCS);
  k_normalize<<<gElem, T, 0, stream>>>((float*)d_out, stats, N);
}